// Round 5
// baseline (124.311 us; speedup 1.0000x reference)
//
#include <hip/hip_runtime.h>
#include <math.h>

#define GRP   4
#define K     9
#define PAD   1
#define C_IN  64
#define CG    16
#define HH    128
#define WW    128
#define BB    4
#define HW    (HH*WW)

typedef __attribute__((ext_vector_type(8))) _Float16 f16x8;
typedef __attribute__((ext_vector_type(2))) _Float16 f16x2;
typedef __attribute__((ext_vector_type(4))) float    f32x4;

union F16Frag { f16x8 f; _Float16 h[8]; f16x2 p[4]; uint w[4]; uint4 q; };

// ws layout: xt fp16 [B][HW][64] = 8,388,608 B | partials 2048*2 f32 | stats 32 f32
#define XT_HALFS   ((size_t)BB * HW * 64)
#define PART_OFF_B (XT_HALFS * 2)
#define STATS_OFF_B (PART_OFF_B + 2048 * 2 * sizeof(float))

// ---- K0: x[B,64,H,W] -> xt[b][pix][64] fp16 ---------------------------------
__global__ __launch_bounds__(256) void transpose_pack(const float* __restrict__ x,
                                                      _Float16* __restrict__ xt)
{
    const int t   = blockIdx.x * 256 + threadIdx.x;   // 262144
    const int qq  = t & 3;
    const int p2  = t >> 2;
    const int pix = p2 & (HW - 1);
    const int b   = p2 >> 14;
    const float* xs = x + ((size_t)b * C_IN + qq * 16) * HW + pix;
    F16Frag f0, f1;
    #pragma unroll
    for (int j = 0; j < 8; ++j) f0.h[j] = (_Float16)xs[(size_t)j * HW];
    #pragma unroll
    for (int j = 0; j < 8; ++j) f1.h[j] = (_Float16)xs[(size_t)(8 + j) * HW];
    uint4* dst = (uint4*)(xt + ((size_t)b * HW + pix) * 64 + qq * 16);
    dst[0] = f0.q;
    dst[1] = f1.q;
}

// ---- K1: MFMA-based fused om-conv + deformable conv + GN partials -----------
// 2048 blocks x 256 thr (4 waves) -> 8 blocks/CU (8 waves/SIMD). Block =
// (bg, image row). Wave = 32 px (2 tiles of 16). Weights in registers.
__global__ __launch_bounds__(256, 8) void dcn_mfma(
    const _Float16* __restrict__ xt,
    const float* __restrict__ w_om,
    const float* __restrict__ b_om,
    const float* __restrict__ dcn_w,     // [G][16co][16ci][9]
    const float* __restrict__ dcn_b,
    const float* __restrict__ offset_scale,
    float* __restrict__ out,
    float* __restrict__ partials)
{
    const int tid = threadIdx.x;
    const int blk = blockIdx.x;
    const int xcd = blk & 7;
    const int q   = blk >> 3;            // 0..255
    const int bg  = xcd * 2 + (q >> 7);
    const int row = q & 127;             // one image row per block
    const int b   = bg >> 2, g = bg & 3;
    const int wave = tid >> 6, lane = tid & 63;
    const int lr = lane & 15;            // fragment row/col index
    const int lj = lane >> 4;            // k-group 0..3

    __shared__ float om_lds[4][16][33];
    __shared__ float red[512];

    // ---- B1 fragments (om weights): col o = nt*16+lr, ch = s*32+lj*8+e ------
    F16Frag B1[2][2];
    #pragma unroll
    for (int s = 0; s < 2; ++s)
    #pragma unroll
    for (int nt = 0; nt < 2; ++nt) {
        const int o = nt * 16 + lr;
        if (o < 27) {
            const float* src = w_om + (size_t)(g * 27 + o) * C_IN + s * 32 + lj * 8;
            #pragma unroll
            for (int e = 0; e < 8; ++e) B1[s][nt].h[e] = (_Float16)src[e];
        } else {
            #pragma unroll
            for (int e = 0; e < 4; ++e) B1[s][nt].w[e] = 0u;
        }
    }
    // ---- B2 fragments (dcn weights): red idx = kp*16+ci ---------------------
    F16Frag B2[5];
    #pragma unroll
    for (int s = 0; s < 5; ++s) {
        const int kp  = 2 * s + (lj >> 1);
        const int cib = (lj & 1) * 8;
        if (kp < 9) {
            const float* src = dcn_w + ((size_t)(g * CG + lr) * CG + cib) * 9 + kp;
            #pragma unroll
            for (int e = 0; e < 8; ++e) B2[s].h[e] = (_Float16)src[(size_t)e * 9];
        } else {
            #pragma unroll
            for (int e = 0; e < 4; ++e) B2[s].w[e] = 0u;
        }
    }

    const float scale = offset_scale[0];
    const float bo0   = b_om[g * 27 + lr];
    const float bo1   = (lr < 11) ? b_om[g * 27 + 16 + lr] : 0.0f;
    const float cbias = dcn_b[g * CG + lr];

    const _Float16* xtb = xt + (size_t)b * HW * 64;
    const _Float16* xg  = xtb + g * CG + (lj & 1) * 8;
    float gs = 0.0f, gss = 0.0f;

    #pragma unroll
    for (int t = 0; t < 2; ++t) {
        const int col0 = wave * 32 + t * 16;
        const int pix0 = row * WW + col0;

        // ---- stage 1: om GEMM ----
        f32x4 C0 = {0, 0, 0, 0}, C1 = {0, 0, 0, 0};
        #pragma unroll
        for (int s = 0; s < 2; ++s) {
            F16Frag A;
            A.q = *(const uint4*)(xtb + (size_t)(pix0 + lr) * 64 + s * 32 + lj * 8);
            C0 = __builtin_amdgcn_mfma_f32_16x16x32_f16(A.f, B1[s][0].f, C0, 0, 0, 0);
            C1 = __builtin_amdgcn_mfma_f32_16x16x32_f16(A.f, B1[s][1].f, C1, 0, 0, 0);
        }
        #pragma unroll
        for (int r = 0; r < 4; ++r) {
            const int prow = lj * 4 + r;
            om_lds[wave][prow][lr] = (C0[r] + bo0) * scale;        // o<16: offsets
            const float v1 = C1[r] + bo1;
            const int o1 = 16 + lr;
            om_lds[wave][prow][o1] = (o1 < 18) ? v1 * scale
                                   : 1.0f / (1.0f + __expf(-v1));  // masks
        }

        // ---- stage 2: sample (pk-f16 blend) + deform GEMM ----
        f32x4 C2 = {cbias, cbias, cbias, cbias};
        #pragma unroll
        for (int s = 0; s < 5; ++s) {
            const int  kp  = 2 * s + (lj >> 1);
            const bool kok = (kp < 9);
            const int  kc  = kok ? kp : 8;
            const float offy = om_lds[wave][lr][2 * kc];
            const float offx = om_lds[wave][lr][2 * kc + 1];
            const float m    = kok ? om_lds[wave][lr][18 + kc] : 0.0f;
            const float py = (float)(row  - PAD + kc / 3) + offy;
            const float px = (float)(col0 + lr - PAD + kc % 3) + offx;

            const float y0f = floorf(py), x0f = floorf(px);
            const int   y0  = (int)y0f,   x0  = (int)x0f;
            const float wy1 = py - y0f,   wx1 = px - x0f;
            const float wy0 = 1.0f - wy1, wx0 = 1.0f - wx1;
            const bool vy0 = (y0 >= 0)  & (y0 <  HH);
            const bool vy1 = (y0 >= -1) & (y0 <  HH - 1);
            const bool vx0 = (x0 >= 0)  & (x0 <  WW);
            const bool vx1 = (x0 >= -1) & (x0 <  WW - 1);
            const int yi0 = min(max(y0,     0), HH - 1);
            const int yi1 = min(max(y0 + 1, 0), HH - 1);
            const int xi0 = min(max(x0,     0), WW - 1);
            const int xi1 = min(max(x0 + 1, 0), WW - 1);
            const float my0 = wy0 * m, my1 = wy1 * m;
            const float w00 = (vy0 & vx0) ? my0 * wx0 : 0.0f;
            const float w01 = (vy0 & vx1) ? my0 * wx1 : 0.0f;
            const float w10 = (vy1 & vx0) ? my1 * wx0 : 0.0f;
            const float w11 = (vy1 & vx1) ? my1 * wx1 : 0.0f;

            F16Frag t00, t01, t10, t11;
            t00.q = *(const uint4*)(xg + (size_t)(yi0 * WW + xi0) * 64);
            t01.q = *(const uint4*)(xg + (size_t)(yi0 * WW + xi1) * 64);
            t10.q = *(const uint4*)(xg + (size_t)(yi1 * WW + xi0) * 64);
            t11.q = *(const uint4*)(xg + (size_t)(yi1 * WW + xi1) * 64);

            const _Float16 h00 = (_Float16)w00, h01 = (_Float16)w01;
            const _Float16 h10 = (_Float16)w10, h11 = (_Float16)w11;
            const f16x2 W00 = {h00, h00}, W01 = {h01, h01};
            const f16x2 W10 = {h10, h10}, W11 = {h11, h11};

            F16Frag A;
            #pragma unroll
            for (int d = 0; d < 4; ++d) {
                f16x2 acc = t00.p[d] * W00;
                acc += t01.p[d] * W01;
                acc += t10.p[d] * W10;
                acc += t11.p[d] * W11;
                A.p[d] = acc;
            }
            C2 = __builtin_amdgcn_mfma_f32_16x16x32_f16(A.f, B2[s].f, C2, 0, 0, 0);
        }

        // ---- store + GN accumulation ----
        float4 st;
        #pragma unroll
        for (int r = 0; r < 4; ++r) {
            const float v = C2[r];
            gs += v; gss += v * v;
            (&st.x)[r] = v;
        }
        *(float4*)(out + ((size_t)b * 64 + g * CG + lr) * HW + pix0 + lj * 4) = st;
    }

    // ---- block GN partial reduction ----
    red[tid] = gs; red[256 + tid] = gss;
    __syncthreads();
    for (int st2 = 128; st2 > 0; st2 >>= 1) {
        if (tid < st2) {
            red[tid]       += red[tid + st2];
            red[256 + tid] += red[256 + tid + st2];
        }
        __syncthreads();
    }
    if (tid == 0) {
        partials[(bg * 128 + row) * 2]     = red[0];
        partials[(bg * 128 + row) * 2 + 1] = red[256];
    }
}

// ---- K2: finalize GN stats --------------------------------------------------
__global__ __launch_bounds__(64) void gn_finalize(const float* __restrict__ partials,
                                                  float* __restrict__ stats)
{
    const int bg = blockIdx.x;
    const int t  = threadIdx.x;
    float s  = partials[(bg * 128 + 2*t) * 2]     + partials[(bg * 128 + 2*t + 1) * 2];
    float ss = partials[(bg * 128 + 2*t) * 2 + 1] + partials[(bg * 128 + 2*t + 1) * 2 + 1];
    #pragma unroll
    for (int off = 32; off > 0; off >>= 1) {
        s  += __shfl_down(s, off);
        ss += __shfl_down(ss, off);
    }
    if (t == 0) {
        const float n   = (float)(CG * HW);
        const float mu  = s / n;
        const float var = ss / n - mu * mu;
        stats[bg * 2]     = mu;
        stats[bg * 2 + 1] = rsqrtf(var + 1e-5f);
    }
}

// ---- K3: in-place GroupNorm apply + exact GELU ------------------------------
__global__ __launch_bounds__(256) void gn_gelu(float* __restrict__ out,
                                               const float* __restrict__ stats,
                                               const float* __restrict__ gn_w,
                                               const float* __restrict__ gn_b)
{
    const int idx = blockIdx.x * 256 + threadIdx.x;   // float4 index
    const int bc  = idx >> 12;
    const int c   = bc & 63;
    const int bg  = ((bc >> 6) << 2) + (c >> 4);

    const float mu = stats[bg * 2];
    const float rs = stats[bg * 2 + 1];
    const float sw = gn_w[c] * rs;
    const float sb = gn_b[c] - mu * sw;

    float4 v = ((const float4*)out)[idx];
    float rr[4] = {v.x, v.y, v.z, v.w};
    #pragma unroll
    for (int jj = 0; jj < 4; ++jj) {
        const float t = rr[jj] * sw + sb;
        rr[jj] = t * 0.5f * (1.0f + erff(t * 0.70710678118654752f));
    }
    ((float4*)out)[idx] = make_float4(rr[0], rr[1], rr[2], rr[3]);
}

// ============================ launch =========================================

extern "C" void kernel_launch(void* const* d_in, const int* in_sizes, int n_in,
                              void* d_out, int out_size, void* d_ws, size_t ws_size,
                              hipStream_t stream) {
    const float* x            = (const float*)d_in[0];
    const float* w_om         = (const float*)d_in[1];
    const float* b_om         = (const float*)d_in[2];
    const float* dcn_w        = (const float*)d_in[3];
    const float* dcn_b        = (const float*)d_in[4];
    const float* gn_w         = (const float*)d_in[5];
    const float* gn_b         = (const float*)d_in[6];
    const float* offset_scale = (const float*)d_in[7];
    float* out = (float*)d_out;

    _Float16* xt    = (_Float16*)d_ws;
    float* partials = (float*)((char*)d_ws + PART_OFF_B);
    float* stats    = (float*)((char*)d_ws + STATS_OFF_B);

    transpose_pack<<<1024, 256, 0, stream>>>(x, xt);
    dcn_mfma<<<2048, 256, 0, stream>>>(xt, w_om, b_om, dcn_w, dcn_b,
                                       offset_scale, out, partials);
    gn_finalize<<<16, 64, 0, stream>>>(partials, stats);
    gn_gelu<<<(BB * 64 * HW / 4) / 256, 256, 0, stream>>>(out, stats, gn_w, gn_b);
}

// Round 6
// 96.409 us; speedup vs baseline: 1.2894x; 1.2894x over previous
//
#include <hip/hip_runtime.h>
#include <math.h>

#define GRP   4
#define K     9
#define PAD   1
#define C_IN  64
#define CG    16
#define HH    128
#define WW    128
#define BB    4
#define HW    (HH*WW)

typedef __attribute__((ext_vector_type(8))) _Float16 f16x8;
typedef __attribute__((ext_vector_type(2))) _Float16 f16x2;
typedef __attribute__((ext_vector_type(4))) float    f32x4;

union F16Frag { f16x8 f; _Float16 h[8]; f16x2 p[4]; uint w[4]; uint4 q; };

// ws layout: xt fp16 [B][HW][64] = 8,388,608 B | partials 2048*2 f32 | stats 32 f32
#define XT_HALFS   ((size_t)BB * HW * 64)
#define PART_OFF_B (XT_HALFS * 2)
#define STATS_OFF_B (PART_OFF_B + 2048 * 2 * sizeof(float))

// ---- K0: x[B,64,H,W] -> xt[b][pix][64] fp16 ---------------------------------
__global__ __launch_bounds__(256) void transpose_pack(const float* __restrict__ x,
                                                      _Float16* __restrict__ xt)
{
    const int t   = blockIdx.x * 256 + threadIdx.x;   // 262144
    const int qq  = t & 3;
    const int p2  = t >> 2;
    const int pix = p2 & (HW - 1);
    const int b   = p2 >> 14;
    const float* xs = x + ((size_t)b * C_IN + qq * 16) * HW + pix;
    F16Frag f0, f1;
    #pragma unroll
    for (int j = 0; j < 8; ++j) f0.h[j] = (_Float16)xs[(size_t)j * HW];
    #pragma unroll
    for (int j = 0; j < 8; ++j) f1.h[j] = (_Float16)xs[(size_t)(8 + j) * HW];
    uint4* dst = (uint4*)(xt + ((size_t)b * HW + pix) * 64 + qq * 16);
    dst[0] = f0.q;
    dst[1] = f1.q;
}

// ---- K1: MFMA-based fused om-conv + deformable conv + GN partials -----------
// 2048 blocks x 256 thr (4 waves). Block = (bg, image row). Wave = 32 px
// (2 tiles of 16). Weights in registers. NOTE: __launch_bounds__(256,4) —
// (256,8) forced a 64-VGPR hard cap -> massive scratch spill (R5: 168MB
// WRITE_SIZE, 124µs). With (256,4) the allocator lands at 64 VGPR naturally
// (R4) and HW can still schedule 8 waves/SIMD when VGPR<=64.
__global__ __launch_bounds__(256, 4) void dcn_mfma(
    const _Float16* __restrict__ xt,
    const float* __restrict__ w_om,
    const float* __restrict__ b_om,
    const float* __restrict__ dcn_w,     // [G][16co][16ci][9]
    const float* __restrict__ dcn_b,
    const float* __restrict__ offset_scale,
    float* __restrict__ out,
    float* __restrict__ partials)
{
    const int tid = threadIdx.x;
    const int blk = blockIdx.x;
    const int xcd = blk & 7;
    const int q   = blk >> 3;            // 0..255
    const int bg  = xcd * 2 + (q >> 7);
    const int row = q & 127;             // one image row per block
    const int b   = bg >> 2, g = bg & 3;
    const int wave = tid >> 6, lane = tid & 63;
    const int lr = lane & 15;            // fragment row/col index
    const int lj = lane >> 4;            // k-group 0..3

    __shared__ float om_lds[4][16][33];
    __shared__ float red[512];

    // ---- B1 fragments (om weights): col o = nt*16+lr, ch = s*32+lj*8+e ------
    F16Frag B1[2][2];
    #pragma unroll
    for (int s = 0; s < 2; ++s)
    #pragma unroll
    for (int nt = 0; nt < 2; ++nt) {
        const int o = nt * 16 + lr;
        if (o < 27) {
            const float* src = w_om + (size_t)(g * 27 + o) * C_IN + s * 32 + lj * 8;
            #pragma unroll
            for (int e = 0; e < 8; ++e) B1[s][nt].h[e] = (_Float16)src[e];
        } else {
            #pragma unroll
            for (int e = 0; e < 4; ++e) B1[s][nt].w[e] = 0u;
        }
    }
    // ---- B2 fragments (dcn weights): red idx = kp*16+ci ---------------------
    F16Frag B2[5];
    #pragma unroll
    for (int s = 0; s < 5; ++s) {
        const int kp  = 2 * s + (lj >> 1);
        const int cib = (lj & 1) * 8;
        if (kp < 9) {
            const float* src = dcn_w + ((size_t)(g * CG + lr) * CG + cib) * 9 + kp;
            #pragma unroll
            for (int e = 0; e < 8; ++e) B2[s].h[e] = (_Float16)src[(size_t)e * 9];
        } else {
            #pragma unroll
            for (int e = 0; e < 4; ++e) B2[s].w[e] = 0u;
        }
    }

    const float scale = offset_scale[0];
    const float bo0   = b_om[g * 27 + lr];
    const float bo1   = (lr < 11) ? b_om[g * 27 + 16 + lr] : 0.0f;
    const float cbias = dcn_b[g * CG + lr];

    const _Float16* xtb = xt + (size_t)b * HW * 64;
    const _Float16* xg  = xtb + g * CG + (lj & 1) * 8;
    float gs = 0.0f, gss = 0.0f;

    #pragma unroll
    for (int t = 0; t < 2; ++t) {
        const int col0 = wave * 32 + t * 16;
        const int pix0 = row * WW + col0;

        // ---- stage 1: om GEMM ----
        f32x4 C0 = {0, 0, 0, 0}, C1 = {0, 0, 0, 0};
        #pragma unroll
        for (int s = 0; s < 2; ++s) {
            F16Frag A;
            A.q = *(const uint4*)(xtb + (size_t)(pix0 + lr) * 64 + s * 32 + lj * 8);
            C0 = __builtin_amdgcn_mfma_f32_16x16x32_f16(A.f, B1[s][0].f, C0, 0, 0, 0);
            C1 = __builtin_amdgcn_mfma_f32_16x16x32_f16(A.f, B1[s][1].f, C1, 0, 0, 0);
        }
        #pragma unroll
        for (int r = 0; r < 4; ++r) {
            const int prow = lj * 4 + r;
            om_lds[wave][prow][lr] = (C0[r] + bo0) * scale;        // o<16: offsets
            const float v1 = C1[r] + bo1;
            const int o1 = 16 + lr;
            om_lds[wave][prow][o1] = (o1 < 18) ? v1 * scale
                                   : 1.0f / (1.0f + __expf(-v1));  // masks
        }

        // ---- stage 2: sample (pk-f16 blend) + deform GEMM ----
        f32x4 C2 = {cbias, cbias, cbias, cbias};
        #pragma unroll
        for (int s = 0; s < 5; ++s) {
            const int  kp  = 2 * s + (lj >> 1);
            const bool kok = (kp < 9);
            const int  kc  = kok ? kp : 8;
            const float offy = om_lds[wave][lr][2 * kc];
            const float offx = om_lds[wave][lr][2 * kc + 1];
            const float m    = kok ? om_lds[wave][lr][18 + kc] : 0.0f;
            const float py = (float)(row  - PAD + kc / 3) + offy;
            const float px = (float)(col0 + lr - PAD + kc % 3) + offx;

            const float y0f = floorf(py), x0f = floorf(px);
            const int   y0  = (int)y0f,   x0  = (int)x0f;
            const float wy1 = py - y0f,   wx1 = px - x0f;
            const float wy0 = 1.0f - wy1, wx0 = 1.0f - wx1;
            const bool vy0 = (y0 >= 0)  & (y0 <  HH);
            const bool vy1 = (y0 >= -1) & (y0 <  HH - 1);
            const bool vx0 = (x0 >= 0)  & (x0 <  WW);
            const bool vx1 = (x0 >= -1) & (x0 <  WW - 1);
            const int yi0 = min(max(y0,     0), HH - 1);
            const int yi1 = min(max(y0 + 1, 0), HH - 1);
            const int xi0 = min(max(x0,     0), WW - 1);
            const int xi1 = min(max(x0 + 1, 0), WW - 1);
            const float my0 = wy0 * m, my1 = wy1 * m;
            const float w00 = (vy0 & vx0) ? my0 * wx0 : 0.0f;
            const float w01 = (vy0 & vx1) ? my0 * wx1 : 0.0f;
            const float w10 = (vy1 & vx0) ? my1 * wx0 : 0.0f;
            const float w11 = (vy1 & vx1) ? my1 * wx1 : 0.0f;

            F16Frag t00, t01, t10, t11;
            t00.q = *(const uint4*)(xg + (size_t)(yi0 * WW + xi0) * 64);
            t01.q = *(const uint4*)(xg + (size_t)(yi0 * WW + xi1) * 64);
            t10.q = *(const uint4*)(xg + (size_t)(yi1 * WW + xi0) * 64);
            t11.q = *(const uint4*)(xg + (size_t)(yi1 * WW + xi1) * 64);

            const _Float16 h00 = (_Float16)w00, h01 = (_Float16)w01;
            const _Float16 h10 = (_Float16)w10, h11 = (_Float16)w11;
            const f16x2 W00 = {h00, h00}, W01 = {h01, h01};
            const f16x2 W10 = {h10, h10}, W11 = {h11, h11};

            F16Frag A;
            #pragma unroll
            for (int d = 0; d < 4; ++d) {
                f16x2 acc = t00.p[d] * W00;
                acc += t01.p[d] * W01;
                acc += t10.p[d] * W10;
                acc += t11.p[d] * W11;
                A.p[d] = acc;
            }
            C2 = __builtin_amdgcn_mfma_f32_16x16x32_f16(A.f, B2[s].f, C2, 0, 0, 0);
        }

        // ---- store + GN accumulation ----
        float4 st;
        #pragma unroll
        for (int r = 0; r < 4; ++r) {
            const float v = C2[r];
            gs += v; gss += v * v;
            (&st.x)[r] = v;
        }
        *(float4*)(out + ((size_t)b * 64 + g * CG + lr) * HW + pix0 + lj * 4) = st;
    }

    // ---- block GN partial reduction ----
    red[tid] = gs; red[256 + tid] = gss;
    __syncthreads();
    for (int st2 = 128; st2 > 0; st2 >>= 1) {
        if (tid < st2) {
            red[tid]       += red[tid + st2];
            red[256 + tid] += red[256 + tid + st2];
        }
        __syncthreads();
    }
    if (tid == 0) {
        partials[(bg * 128 + row) * 2]     = red[0];
        partials[(bg * 128 + row) * 2 + 1] = red[256];
    }
}

// ---- K2: finalize GN stats --------------------------------------------------
__global__ __launch_bounds__(64) void gn_finalize(const float* __restrict__ partials,
                                                  float* __restrict__ stats)
{
    const int bg = blockIdx.x;
    const int t  = threadIdx.x;
    float s  = partials[(bg * 128 + 2*t) * 2]     + partials[(bg * 128 + 2*t + 1) * 2];
    float ss = partials[(bg * 128 + 2*t) * 2 + 1] + partials[(bg * 128 + 2*t + 1) * 2 + 1];
    #pragma unroll
    for (int off = 32; off > 0; off >>= 1) {
        s  += __shfl_down(s, off);
        ss += __shfl_down(ss, off);
    }
    if (t == 0) {
        const float n   = (float)(CG * HW);
        const float mu  = s / n;
        const float var = ss / n - mu * mu;
        stats[bg * 2]     = mu;
        stats[bg * 2 + 1] = rsqrtf(var + 1e-5f);
    }
}

// ---- K3: in-place GroupNorm apply + exact GELU ------------------------------
__global__ __launch_bounds__(256) void gn_gelu(float* __restrict__ out,
                                               const float* __restrict__ stats,
                                               const float* __restrict__ gn_w,
                                               const float* __restrict__ gn_b)
{
    const int idx = blockIdx.x * 256 + threadIdx.x;   // float4 index
    const int bc  = idx >> 12;
    const int c   = bc & 63;
    const int bg  = ((bc >> 6) << 2) + (c >> 4);

    const float mu = stats[bg * 2];
    const float rs = stats[bg * 2 + 1];
    const float sw = gn_w[c] * rs;
    const float sb = gn_b[c] - mu * sw;

    float4 v = ((const float4*)out)[idx];
    float rr[4] = {v.x, v.y, v.z, v.w};
    #pragma unroll
    for (int jj = 0; jj < 4; ++jj) {
        const float t = rr[jj] * sw + sb;
        rr[jj] = t * 0.5f * (1.0f + erff(t * 0.70710678118654752f));
    }
    ((float4*)out)[idx] = make_float4(rr[0], rr[1], rr[2], rr[3]);
}

// ============================ launch =========================================

extern "C" void kernel_launch(void* const* d_in, const int* in_sizes, int n_in,
                              void* d_out, int out_size, void* d_ws, size_t ws_size,
                              hipStream_t stream) {
    const float* x            = (const float*)d_in[0];
    const float* w_om         = (const float*)d_in[1];
    const float* b_om         = (const float*)d_in[2];
    const float* dcn_w        = (const float*)d_in[3];
    const float* dcn_b        = (const float*)d_in[4];
    const float* gn_w         = (const float*)d_in[5];
    const float* gn_b         = (const float*)d_in[6];
    const float* offset_scale = (const float*)d_in[7];
    float* out = (float*)d_out;

    _Float16* xt    = (_Float16*)d_ws;
    float* partials = (float*)((char*)d_ws + PART_OFF_B);
    float* stats    = (float*)((char*)d_ws + STATS_OFF_B);

    transpose_pack<<<1024, 256, 0, stream>>>(x, xt);
    dcn_mfma<<<2048, 256, 0, stream>>>(xt, w_om, b_om, dcn_w, dcn_b,
                                       offset_scale, out, partials);
    gn_finalize<<<16, 64, 0, stream>>>(partials, stats);
    gn_gelu<<<(BB * 64 * HW / 4) / 256, 256, 0, stream>>>(out, stats, gn_w, gn_b);
}

// Round 7
// 74.215 us; speedup vs baseline: 1.6750x; 1.2990x over previous
//
#include <hip/hip_runtime.h>
#include <math.h>

#define GRP   4
#define K     9
#define PAD   1
#define C_IN  64
#define CG    16
#define HH    128
#define WW    128
#define BB    4
#define HW    (HH*WW)

typedef __attribute__((ext_vector_type(8))) _Float16 f16x8;
typedef __attribute__((ext_vector_type(2))) _Float16 f16x2;
typedef __attribute__((ext_vector_type(4))) float    f32x4;

union F16Frag { f16x8 f; _Float16 h[8]; f16x2 p[4]; uint w[4]; uint4 q; };
union YX      { uint u; f16x2 h2; };

// ---------------- ws layout --------------------------------------------------
// new path: xt | om16 | frags1 | frags2 | partials | stats
#define XT_OFF     0
#define XT_BYTES   ((size_t)BB * HW * 64 * 2)               //  8,388,608
#define OM_OFF     XT_BYTES
#define OM_BYTES   ((size_t)16 * HW * 28 * 2)               // 14,680,064
#define FR1_OFF    (OM_OFF + OM_BYTES)
#define FR1_BYTES  (14 * 64 * 16)                           //     14,336
#define FR2_OFF    (FR1_OFF + FR1_BYTES)
#define FR2_BYTES  (20 * 64 * 16)                           //     20,480
#define PART_OFF   (FR2_OFF + FR2_BYTES)
#define PART_BYTES (2048 * 2 * 4)
#define STATS_OFF  (PART_OFF + PART_BYTES)
#define NEED_BYTES (STATS_OFF + 128)
// fallback path: xt | partials | stats   (proven budget, ws >= 16.79 MB known)
#define FB_PART_OFF  XT_BYTES
#define FB_STATS_OFF (XT_BYTES + 1024 * 2 * 4)

// ---- K0: x[B,64,H,W] -> xt[b][pix][64] fp16 ---------------------------------
__global__ __launch_bounds__(256) void transpose_pack(const float* __restrict__ x,
                                                      _Float16* __restrict__ xt)
{
    const int t   = blockIdx.x * 256 + threadIdx.x;   // 262144
    const int qq  = t & 3;
    const int p2  = t >> 2;
    const int pix = p2 & (HW - 1);
    const int b   = p2 >> 14;
    const float* xs = x + ((size_t)b * C_IN + qq * 16) * HW + pix;
    F16Frag f0, f1;
    #pragma unroll
    for (int j = 0; j < 8; ++j) f0.h[j] = (_Float16)xs[(size_t)j * HW];
    #pragma unroll
    for (int j = 0; j < 8; ++j) f1.h[j] = (_Float16)xs[(size_t)(8 + j) * HW];
    uint4* dst = (uint4*)(xt + ((size_t)b * HW + pix) * 64 + qq * 16);
    dst[0] = f0.q;
    dst[1] = f1.q;
}

// ---- K0b: precompute MFMA weight fragments ----------------------------------
// frags1[nt*2+s][lane]: om-GEMM B fragment, col = nt*16+lr over 112=4*28 cols,
//                       k-elem = s*32+lj*8+e = input channel.
// frags2[g*5+s][lane]:  dcn B fragment, col co=lr, k = kp*16+ci.
__global__ __launch_bounds__(256) void make_frags(const float* __restrict__ w_om,
                                                  const float* __restrict__ dcn_w,
                                                  uint4* __restrict__ frags1,
                                                  uint4* __restrict__ frags2)
{
    const int t    = blockIdx.x * 256 + threadIdx.x;
    const int lane = t & 63;
    const int lr   = lane & 15, lj = lane >> 4;
    const int f    = t >> 6;
    F16Frag r;
    #pragma unroll
    for (int e = 0; e < 4; ++e) r.w[e] = 0u;
    if (f < 14) {                          // frags1: f = nt*2+s
        const int nt = f >> 1, s = f & 1;
        const int col = nt * 16 + lr;
        const int g = col / 28, oo = col - 28 * g;
        if (oo < 27) {
            const float* src = w_om + (size_t)(g * 27 + oo) * C_IN + s * 32 + lj * 8;
            #pragma unroll
            for (int e = 0; e < 8; ++e) r.h[e] = (_Float16)src[e];
        }
        frags1[f * 64 + lane] = r.q;
    } else if (f < 34) {                   // frags2: f-14 = g*5+s
        const int f2 = f - 14;
        const int g = f2 / 5, s = f2 - 5 * g;
        const int kp = 2 * s + (lj >> 1);
        const int cib = (lj & 1) * 8;
        if (kp < 9) {
            #pragma unroll
            for (int e = 0; e < 8; ++e)
                r.h[e] = (_Float16)dcn_w[((size_t)(g * CG + lr) * CG + cib + e) * 9 + kp];
        }
        frags2[f2 * 64 + lane] = r.q;
    }
}

// ---- K1: om GEMM -> om16[bg][pix][28] fp16 (offsets pre-scaled, masks sigmoid)
// 1024 blocks x 4 waves; wave = 1 tile of 16 px x 112 cols (7 nt x 2 k-step).
__global__ __launch_bounds__(256, 4) void om_gemm(
    const _Float16* __restrict__ xt,
    const uint4* __restrict__ frags1,
    const float* __restrict__ b_om,
    const float* __restrict__ offset_scale,
    _Float16* __restrict__ om16)
{
    const int tid  = threadIdx.x;
    const int wave = tid >> 6, lane = tid & 63;
    const int lr   = lane & 15, lj = lane >> 4;
    const int bpix0 = blockIdx.x * 64 + wave * 16;     // flat pixel over B*HW
    const int b     = bpix0 >> 14;
    const int pixb  = bpix0 & (HW - 1);
    const float scale = offset_scale[0];

    // per-(lane,nt) metadata
    int g_[7], oo_[7];
    float bo_[7];
    #pragma unroll
    for (int nt = 0; nt < 7; ++nt) {
        const int col = nt * 16 + lr;
        const int g = col / 28, oo = col - 28 * g;
        g_[nt] = g; oo_[nt] = oo;
        bo_[nt] = (oo < 27) ? b_om[g * 27 + oo] : 0.0f;
    }

    F16Frag A0, A1;
    A0.q = *(const uint4*)(xt + (size_t)(bpix0 + lr) * 64 + lj * 8);
    A1.q = *(const uint4*)(xt + (size_t)(bpix0 + lr) * 64 + 32 + lj * 8);

    #pragma unroll
    for (int nt = 0; nt < 7; ++nt) {
        F16Frag B0, B1;
        B0.q = frags1[(nt * 2 + 0) * 64 + lane];
        B1.q = frags1[(nt * 2 + 1) * 64 + lane];
        f32x4 C = {0, 0, 0, 0};
        C = __builtin_amdgcn_mfma_f32_16x16x32_f16(A0.f, B0.f, C, 0, 0, 0);
        C = __builtin_amdgcn_mfma_f32_16x16x32_f16(A1.f, B1.f, C, 0, 0, 0);
        const int g = g_[nt], oo = oo_[nt];
        if (oo < 27) {
            const size_t base = ((size_t)(b * 4 + g) * HW + pixb + lj * 4);
            #pragma unroll
            for (int r = 0; r < 4; ++r) {
                float v = C[r] + bo_[nt];
                v = (oo < 18) ? v * scale : 1.0f / (1.0f + __expf(-v));
                om16[(base + r) * 28 + oo] = (_Float16)v;
            }
        }
    }
}

// ---- K2: deformable-conv sampling + PV GEMM + GN partials -------------------
// 2048 blocks x 4 waves; block = (bg, image row); wave = 32 px (2 tiles of 16).
__global__ __launch_bounds__(256, 4) void dcn_sample(
    const _Float16* __restrict__ xt,
    const _Float16* __restrict__ om16,
    const uint4* __restrict__ frags2,
    const float* __restrict__ dcn_b,
    float* __restrict__ out,
    float* __restrict__ partials)
{
    const int tid = threadIdx.x;
    const int blk = blockIdx.x;
    const int xcd = blk & 7;
    const int q   = blk >> 3;            // 0..255
    const int bg  = xcd * 2 + (q >> 7);
    const int row = q & 127;
    const int b   = bg >> 2, g = bg & 3;
    const int wave = tid >> 6, lane = tid & 63;
    const int lr = lane & 15;
    const int lj = lane >> 4;

    __shared__ float red[512];

    F16Frag B2[5];
    #pragma unroll
    for (int s = 0; s < 5; ++s) B2[s].q = frags2[(g * 5 + s) * 64 + lane];
    const float cbias = dcn_b[g * CG + lr];

    const _Float16* xtb = xt + (size_t)b * HW * 64;
    const _Float16* xg  = xtb + g * CG + (lj & 1) * 8;
    const uint* omw = (const uint*)om16;
    float gs = 0.0f, gss = 0.0f;

    #pragma unroll
    for (int t = 0; t < 2; ++t) {
        const int col0 = wave * 32 + t * 16;
        const int pix0 = row * WW + col0;
        const int p    = (bg << 14) + pix0 + lr;   // om record index

        f32x4 C2 = {cbias, cbias, cbias, cbias};
        #pragma unroll
        for (int s = 0; s < 5; ++s) {
            const int  kp  = 2 * s + (lj >> 1);
            const bool kok = (kp < 9);
            const int  kc  = kok ? kp : 8;

            YX yx; yx.u = omw[p * 14 + kc];
            const float offy = (float)yx.h2[0];
            const float offx = (float)yx.h2[1];
            const float m    = kok ? (float)om16[(size_t)p * 28 + 18 + kc] : 0.0f;

            const float py = (float)(row        - PAD + kc / 3) + offy;
            const float px = (float)(col0 + lr  - PAD + kc % 3) + offx;

            const float y0f = floorf(py), x0f = floorf(px);
            const int   y0  = (int)y0f,   x0  = (int)x0f;
            const float wy1 = py - y0f,   wx1 = px - x0f;
            const float wy0 = 1.0f - wy1, wx0 = 1.0f - wx1;
            const bool vy0 = (y0 >= 0)  & (y0 <  HH);
            const bool vy1 = (y0 >= -1) & (y0 <  HH - 1);
            const bool vx0 = (x0 >= 0)  & (x0 <  WW);
            const bool vx1 = (x0 >= -1) & (x0 <  WW - 1);
            const int yi0 = min(max(y0,     0), HH - 1);
            const int yi1 = min(max(y0 + 1, 0), HH - 1);
            const int xi0 = min(max(x0,     0), WW - 1);
            const int xi1 = min(max(x0 + 1, 0), WW - 1);
            const float my0 = wy0 * m, my1 = wy1 * m;
            const float w00 = (vy0 & vx0) ? my0 * wx0 : 0.0f;
            const float w01 = (vy0 & vx1) ? my0 * wx1 : 0.0f;
            const float w10 = (vy1 & vx0) ? my1 * wx0 : 0.0f;
            const float w11 = (vy1 & vx1) ? my1 * wx1 : 0.0f;

            F16Frag t00, t01, t10, t11;
            t00.q = *(const uint4*)(xg + (size_t)(yi0 * WW + xi0) * 64);
            t01.q = *(const uint4*)(xg + (size_t)(yi0 * WW + xi1) * 64);
            t10.q = *(const uint4*)(xg + (size_t)(yi1 * WW + xi0) * 64);
            t11.q = *(const uint4*)(xg + (size_t)(yi1 * WW + xi1) * 64);

            const _Float16 h00 = (_Float16)w00, h01 = (_Float16)w01;
            const _Float16 h10 = (_Float16)w10, h11 = (_Float16)w11;
            const f16x2 W00 = {h00, h00}, W01 = {h01, h01};
            const f16x2 W10 = {h10, h10}, W11 = {h11, h11};

            F16Frag A;
            #pragma unroll
            for (int d = 0; d < 4; ++d) {
                f16x2 acc = t00.p[d] * W00;
                acc += t01.p[d] * W01;
                acc += t10.p[d] * W10;
                acc += t11.p[d] * W11;
                A.p[d] = acc;
            }
            C2 = __builtin_amdgcn_mfma_f32_16x16x32_f16(A.f, B2[s].f, C2, 0, 0, 0);
        }

        float4 st;
        #pragma unroll
        for (int r = 0; r < 4; ++r) {
            const float v = C2[r];
            gs += v; gss += v * v;
            (&st.x)[r] = v;
        }
        *(float4*)(out + ((size_t)b * 64 + g * CG + lr) * HW + pix0 + lj * 4) = st;
    }

    red[tid] = gs; red[256 + tid] = gss;
    __syncthreads();
    for (int st2 = 128; st2 > 0; st2 >>= 1) {
        if (tid < st2) {
            red[tid]       += red[tid + st2];
            red[256 + tid] += red[256 + tid + st2];
        }
        __syncthreads();
    }
    if (tid == 0) {
        partials[(bg * 128 + row) * 2]     = red[0];
        partials[(bg * 128 + row) * 2 + 1] = red[256];
    }
}

// ---- fallback: R4-geometry fused kernel (1024 blocks x 4 tiles/wave) --------
__global__ __launch_bounds__(256, 4) void dcn_fused_fb(
    const _Float16* __restrict__ xt,
    const float* __restrict__ w_om,
    const float* __restrict__ b_om,
    const float* __restrict__ dcn_w,
    const float* __restrict__ dcn_b,
    const float* __restrict__ offset_scale,
    float* __restrict__ out,
    float* __restrict__ partials)
{
    const int tid = threadIdx.x;
    const int blk = blockIdx.x;
    const int xcd = blk & 7;
    const int q   = blk >> 3;            // 0..127
    const int bg  = xcd * 2 + (q >> 6);
    const int tb  = q & 63;
    const int b   = bg >> 2, g = bg & 3;
    const int wave = tid >> 6, lane = tid & 63;
    const int lr = lane & 15, lj = lane >> 4;

    __shared__ float om_lds[4][16][33];
    __shared__ float red[512];

    F16Frag B1[2][2];
    #pragma unroll
    for (int s = 0; s < 2; ++s)
    #pragma unroll
    for (int nt = 0; nt < 2; ++nt) {
        const int o = nt * 16 + lr;
        if (o < 27) {
            const float* src = w_om + (size_t)(g * 27 + o) * C_IN + s * 32 + lj * 8;
            #pragma unroll
            for (int e = 0; e < 8; ++e) B1[s][nt].h[e] = (_Float16)src[e];
        } else {
            #pragma unroll
            for (int e = 0; e < 4; ++e) B1[s][nt].w[e] = 0u;
        }
    }
    F16Frag B2[5];
    #pragma unroll
    for (int s = 0; s < 5; ++s) {
        const int kp  = 2 * s + (lj >> 1);
        const int cib = (lj & 1) * 8;
        if (kp < 9) {
            const float* src = dcn_w + ((size_t)(g * CG + lr) * CG + cib) * 9 + kp;
            #pragma unroll
            for (int e = 0; e < 8; ++e) B2[s].h[e] = (_Float16)src[(size_t)e * 9];
        } else {
            #pragma unroll
            for (int e = 0; e < 4; ++e) B2[s].w[e] = 0u;
        }
    }

    const float scale = offset_scale[0];
    const float bo0   = b_om[g * 27 + lr];
    const float bo1   = (lr < 11) ? b_om[g * 27 + 16 + lr] : 0.0f;
    const float cbias = dcn_b[g * CG + lr];

    const _Float16* xtb = xt + (size_t)b * HW * 64;
    const _Float16* xg  = xtb + g * CG + (lj & 1) * 8;
    float gs = 0.0f, gss = 0.0f;

    for (int t = 0; t < 4; ++t) {
        const int pix0 = tb * 256 + wave * 64 + t * 16;
        const int row  = pix0 >> 7;
        const int col0 = pix0 & 127;

        f32x4 C0 = {0, 0, 0, 0}, C1 = {0, 0, 0, 0};
        #pragma unroll
        for (int s = 0; s < 2; ++s) {
            F16Frag A;
            A.q = *(const uint4*)(xtb + (size_t)(pix0 + lr) * 64 + s * 32 + lj * 8);
            C0 = __builtin_amdgcn_mfma_f32_16x16x32_f16(A.f, B1[s][0].f, C0, 0, 0, 0);
            C1 = __builtin_amdgcn_mfma_f32_16x16x32_f16(A.f, B1[s][1].f, C1, 0, 0, 0);
        }
        #pragma unroll
        for (int r = 0; r < 4; ++r) {
            const int prow = lj * 4 + r;
            om_lds[wave][prow][lr] = (C0[r] + bo0) * scale;
            const float v1 = C1[r] + bo1;
            const int o1 = 16 + lr;
            om_lds[wave][prow][o1] = (o1 < 18) ? v1 * scale
                                   : 1.0f / (1.0f + __expf(-v1));
        }

        f32x4 C2 = {cbias, cbias, cbias, cbias};
        #pragma unroll
        for (int s = 0; s < 5; ++s) {
            const int  kp  = 2 * s + (lj >> 1);
            const bool kok = (kp < 9);
            const int  kc  = kok ? kp : 8;
            const float offy = om_lds[wave][lr][2 * kc];
            const float offx = om_lds[wave][lr][2 * kc + 1];
            const float m    = kok ? om_lds[wave][lr][18 + kc] : 0.0f;
            const float py = (float)(row  - PAD + kc / 3) + offy;
            const float px = (float)(col0 + lr - PAD + kc % 3) + offx;

            const float y0f = floorf(py), x0f = floorf(px);
            const int   y0  = (int)y0f,   x0  = (int)x0f;
            const float wy1 = py - y0f,   wx1 = px - x0f;
            const float wy0 = 1.0f - wy1, wx0 = 1.0f - wx1;
            const bool vy0 = (y0 >= 0)  & (y0 <  HH);
            const bool vy1 = (y0 >= -1) & (y0 <  HH - 1);
            const bool vx0 = (x0 >= 0)  & (x0 <  WW);
            const bool vx1 = (x0 >= -1) & (x0 <  WW - 1);
            const int yi0 = min(max(y0,     0), HH - 1);
            const int yi1 = min(max(y0 + 1, 0), HH - 1);
            const int xi0 = min(max(x0,     0), WW - 1);
            const int xi1 = min(max(x0 + 1, 0), WW - 1);
            const float my0 = wy0 * m, my1 = wy1 * m;
            const float w00 = (vy0 & vx0) ? my0 * wx0 : 0.0f;
            const float w01 = (vy0 & vx1) ? my0 * wx1 : 0.0f;
            const float w10 = (vy1 & vx0) ? my1 * wx0 : 0.0f;
            const float w11 = (vy1 & vx1) ? my1 * wx1 : 0.0f;

            F16Frag t00, t01, t10, t11;
            t00.q = *(const uint4*)(xg + (size_t)(yi0 * WW + xi0) * 64);
            t01.q = *(const uint4*)(xg + (size_t)(yi0 * WW + xi1) * 64);
            t10.q = *(const uint4*)(xg + (size_t)(yi1 * WW + xi0) * 64);
            t11.q = *(const uint4*)(xg + (size_t)(yi1 * WW + xi1) * 64);

            const _Float16 h00 = (_Float16)w00, h01 = (_Float16)w01;
            const _Float16 h10 = (_Float16)w10, h11 = (_Float16)w11;
            const f16x2 W00 = {h00, h00}, W01 = {h01, h01};
            const f16x2 W10 = {h10, h10}, W11 = {h11, h11};

            F16Frag A;
            #pragma unroll
            for (int d = 0; d < 4; ++d) {
                f16x2 acc = t00.p[d] * W00;
                acc += t01.p[d] * W01;
                acc += t10.p[d] * W10;
                acc += t11.p[d] * W11;
                A.p[d] = acc;
            }
            C2 = __builtin_amdgcn_mfma_f32_16x16x32_f16(A.f, B2[s].f, C2, 0, 0, 0);
        }

        float4 st;
        #pragma unroll
        for (int r = 0; r < 4; ++r) {
            const float v = C2[r];
            gs += v; gss += v * v;
            (&st.x)[r] = v;
        }
        *(float4*)(out + ((size_t)b * 64 + g * CG + lr) * HW + pix0 + lj * 4) = st;
    }

    red[tid] = gs; red[256 + tid] = gss;
    __syncthreads();
    for (int st2 = 128; st2 > 0; st2 >>= 1) {
        if (tid < st2) {
            red[tid]       += red[tid + st2];
            red[256 + tid] += red[256 + tid + st2];
        }
        __syncthreads();
    }
    if (tid == 0) {
        partials[(bg * 64 + tb) * 2]     = red[0];
        partials[(bg * 64 + tb) * 2 + 1] = red[256];
    }
}

// ---- finalize GN stats (per_bg = partial entries per bg) --------------------
__global__ __launch_bounds__(64) void gn_finalize(const float* __restrict__ partials,
                                                  float* __restrict__ stats,
                                                  int per_bg)
{
    const int bg = blockIdx.x;
    const int t  = threadIdx.x;
    float s = 0.0f, ss = 0.0f;
    for (int i = t; i < per_bg; i += 64) {
        s  += partials[(bg * per_bg + i) * 2];
        ss += partials[(bg * per_bg + i) * 2 + 1];
    }
    #pragma unroll
    for (int off = 32; off > 0; off >>= 1) {
        s  += __shfl_down(s, off);
        ss += __shfl_down(ss, off);
    }
    if (t == 0) {
        const float n   = (float)(CG * HW);
        const float mu  = s / n;
        const float var = ss / n - mu * mu;
        stats[bg * 2]     = mu;
        stats[bg * 2 + 1] = rsqrtf(var + 1e-5f);
    }
}

// ---- GroupNorm apply + exact GELU -------------------------------------------
__global__ __launch_bounds__(256) void gn_gelu(float* __restrict__ out,
                                               const float* __restrict__ stats,
                                               const float* __restrict__ gn_w,
                                               const float* __restrict__ gn_b)
{
    const int idx = blockIdx.x * 256 + threadIdx.x;   // float4 index
    const int bc  = idx >> 12;
    const int c   = bc & 63;
    const int bg  = ((bc >> 6) << 2) + (c >> 4);

    const float mu = stats[bg * 2];
    const float rs = stats[bg * 2 + 1];
    const float sw = gn_w[c] * rs;
    const float sb = gn_b[c] - mu * sw;

    float4 v = ((const float4*)out)[idx];
    float rr[4] = {v.x, v.y, v.z, v.w};
    #pragma unroll
    for (int jj = 0; jj < 4; ++jj) {
        const float t = rr[jj] * sw + sb;
        rr[jj] = t * 0.5f * (1.0f + erff(t * 0.70710678118654752f));
    }
    ((float4*)out)[idx] = make_float4(rr[0], rr[1], rr[2], rr[3]);
}

// ============================ launch =========================================

extern "C" void kernel_launch(void* const* d_in, const int* in_sizes, int n_in,
                              void* d_out, int out_size, void* d_ws, size_t ws_size,
                              hipStream_t stream) {
    const float* x            = (const float*)d_in[0];
    const float* w_om         = (const float*)d_in[1];
    const float* b_om         = (const float*)d_in[2];
    const float* dcn_w        = (const float*)d_in[3];
    const float* dcn_b        = (const float*)d_in[4];
    const float* gn_w         = (const float*)d_in[5];
    const float* gn_b         = (const float*)d_in[6];
    const float* offset_scale = (const float*)d_in[7];
    float* out = (float*)d_out;
    char*  ws  = (char*)d_ws;

    _Float16* xt = (_Float16*)(ws + XT_OFF);
    transpose_pack<<<1024, 256, 0, stream>>>(x, xt);

    if (ws_size >= NEED_BYTES) {
        _Float16* om16   = (_Float16*)(ws + OM_OFF);
        uint4* frags1    = (uint4*)(ws + FR1_OFF);
        uint4* frags2    = (uint4*)(ws + FR2_OFF);
        float* partials  = (float*)(ws + PART_OFF);
        float* stats     = (float*)(ws + STATS_OFF);

        make_frags<<<9, 256, 0, stream>>>(w_om, dcn_w, frags1, frags2);
        om_gemm<<<1024, 256, 0, stream>>>(xt, frags1, b_om, offset_scale, om16);
        dcn_sample<<<2048, 256, 0, stream>>>(xt, om16, frags2, dcn_b, out, partials);
        gn_finalize<<<16, 64, 0, stream>>>(partials, stats, 128);
        gn_gelu<<<(BB * 64 * HW / 4) / 256, 256, 0, stream>>>(out, stats, gn_w, gn_b);
    } else {
        float* partials = (float*)(ws + FB_PART_OFF);
        float* stats    = (float*)(ws + FB_STATS_OFF);
        dcn_fused_fb<<<1024, 256, 0, stream>>>(xt, w_om, b_om, dcn_w, dcn_b,
                                               offset_scale, out, partials);
        gn_finalize<<<16, 64, 0, stream>>>(partials, stats, 64);
        gn_gelu<<<(BB * 64 * HW / 4) / 256, 256, 0, stream>>>(out, stats, gn_w, gn_b);
    }
}

// Round 8
// 72.642 us; speedup vs baseline: 1.7113x; 1.0217x over previous
//
#include <hip/hip_runtime.h>
#include <math.h>

#define GRP   4
#define K     9
#define PAD   1
#define C_IN  64
#define CG    16
#define HH    128
#define WW    128
#define BB    4
#define HW    (HH*WW)

typedef __attribute__((ext_vector_type(8))) _Float16 f16x8;
typedef __attribute__((ext_vector_type(2))) _Float16 f16x2;
typedef __attribute__((ext_vector_type(4))) float    f32x4;

union F16Frag { f16x8 f; _Float16 h[8]; f16x2 p[4]; uint w[4]; uint4 q; };
union YX      { uint u; f16x2 h2; };

// ---------------- ws layout --------------------------------------------------
#define XT_OFF     0
#define XT_BYTES   ((size_t)BB * HW * 64 * 2)               //  8,388,608
#define OM_OFF     XT_BYTES
#define OM_BYTES   ((size_t)16 * HW * 28 * 2)               // 14,680,064
#define FR1_OFF    (OM_OFF + OM_BYTES)
#define FR1_BYTES  (14 * 64 * 16)
#define FR2_OFF    (FR1_OFF + FR1_BYTES)
#define FR2_BYTES  (20 * 64 * 16)
#define PART_OFF   (FR2_OFF + FR2_BYTES)
#define PART_BYTES (2048 * 2 * 4)
#define STATS_OFF  (PART_OFF + PART_BYTES)
#define NEED_BYTES (STATS_OFF + 128)
// fallback path offsets
#define FB_PART_OFF  XT_BYTES
#define FB_STATS_OFF (XT_BYTES + 1024 * 2 * 4)

// ---- make_frags: precompute MFMA weight fragments ---------------------------
__global__ __launch_bounds__(256) void make_frags(const float* __restrict__ w_om,
                                                  const float* __restrict__ dcn_w,
                                                  uint4* __restrict__ frags1,
                                                  uint4* __restrict__ frags2)
{
    const int t    = blockIdx.x * 256 + threadIdx.x;
    const int lane = t & 63;
    const int lr   = lane & 15, lj = lane >> 4;
    const int f    = t >> 6;
    F16Frag r;
    #pragma unroll
    for (int e = 0; e < 4; ++e) r.w[e] = 0u;
    if (f < 14) {                          // frags1: f = nt*2+s
        const int nt = f >> 1, s = f & 1;
        const int col = nt * 16 + lr;
        const int g = col / 28, oo = col - 28 * g;
        if (oo < 27) {
            const float* src = w_om + (size_t)(g * 27 + oo) * C_IN + s * 32 + lj * 8;
            #pragma unroll
            for (int e = 0; e < 8; ++e) r.h[e] = (_Float16)src[e];
        }
        frags1[f * 64 + lane] = r.q;
    } else if (f < 34) {                   // frags2: f-14 = g*5+s
        const int f2 = f - 14;
        const int g = f2 / 5, s = f2 - 5 * g;
        const int kp = 2 * s + (lj >> 1);
        const int cib = (lj & 1) * 8;
        if (kp < 9) {
            #pragma unroll
            for (int e = 0; e < 8; ++e)
                r.h[e] = (_Float16)dcn_w[((size_t)(g * CG + lr) * CG + cib + e) * 9 + kp];
        }
        frags2[f2 * 64 + lane] = r.q;
    }
}

// ---- om_gemm_t: transpose-gather from x + om GEMM + xt write ----------------
// 1024 blocks x 4 waves; wave = 16 px. Lane builds its A-fragments straight
// from x (16 strided f32 loads = the transpose), writes them to xt, then runs
// the om GEMM (7 col-tiles x 2 k-steps) writing om16[bg][pix][28].
__global__ __launch_bounds__(256, 4) void om_gemm_t(
    const float* __restrict__ x,
    const uint4* __restrict__ frags1,
    const float* __restrict__ b_om,
    const float* __restrict__ offset_scale,
    _Float16* __restrict__ xt,
    _Float16* __restrict__ om16)
{
    const int tid  = threadIdx.x;
    const int wave = tid >> 6, lane = tid & 63;
    const int lr   = lane & 15, lj = lane >> 4;
    const int bpix0   = blockIdx.x * 64 + wave * 16;   // flat pixel over B*HW
    const int pixflat = bpix0 + lr;
    const int b       = pixflat >> 14;
    const int pixb    = pixflat & (HW - 1);
    const float scale = offset_scale[0];

    // transpose gather: 16 strided loads -> two fragments
    const float* xs = x + (size_t)b * C_IN * HW + pixb;
    F16Frag A0, A1;
    #pragma unroll
    for (int e = 0; e < 8; ++e) A0.h[e] = (_Float16)xs[(size_t)(lj * 8 + e) * HW];
    #pragma unroll
    for (int e = 0; e < 8; ++e) A1.h[e] = (_Float16)xs[(size_t)(32 + lj * 8 + e) * HW];
    *(uint4*)(xt + (size_t)pixflat * 64 + lj * 8)      = A0.q;
    *(uint4*)(xt + (size_t)pixflat * 64 + 32 + lj * 8) = A1.q;

    // per-(lane,nt) metadata
    int g_[7], oo_[7];
    float bo_[7];
    #pragma unroll
    for (int nt = 0; nt < 7; ++nt) {
        const int col = nt * 16 + lr;
        const int g = col / 28, oo = col - 28 * g;
        g_[nt] = g; oo_[nt] = oo;
        bo_[nt] = (oo < 27) ? b_om[g * 27 + oo] : 0.0f;
    }

    const int bq = bpix0 >> 14;
    const int pq = bpix0 & (HW - 1);
    #pragma unroll
    for (int nt = 0; nt < 7; ++nt) {
        F16Frag B0, B1;
        B0.q = frags1[(nt * 2 + 0) * 64 + lane];
        B1.q = frags1[(nt * 2 + 1) * 64 + lane];
        f32x4 C = {0, 0, 0, 0};
        C = __builtin_amdgcn_mfma_f32_16x16x32_f16(A0.f, B0.f, C, 0, 0, 0);
        C = __builtin_amdgcn_mfma_f32_16x16x32_f16(A1.f, B1.f, C, 0, 0, 0);
        const int g = g_[nt], oo = oo_[nt];
        if (oo < 27) {
            const size_t base = ((size_t)(bq * 4 + g) * HW + pq + lj * 4);
            #pragma unroll
            for (int r = 0; r < 4; ++r) {
                float v = C[r] + bo_[nt];
                v = (oo < 18) ? v * scale : 1.0f / (1.0f + __expf(-v));
                om16[(base + r) * 28 + oo] = (_Float16)v;
            }
        }
    }
}

// ---- dcn_sample: sampling + PV GEMM + GN partials ---------------------------
// 2048 blocks x 4 waves; block = (bg,row); wave = 32 px (2 tiles of 16).
// All om data for both tiles is prefetched into registers before the k-loops,
// so each k-step's tap addresses depend only on registers (1 load latency).
__global__ __launch_bounds__(256, 4) void dcn_sample(
    const _Float16* __restrict__ xt,
    const _Float16* __restrict__ om16,
    const uint4* __restrict__ frags2,
    const float* __restrict__ dcn_b,
    float* __restrict__ out,
    float* __restrict__ partials)
{
    const int tid = threadIdx.x;
    const int blk = blockIdx.x;
    const int xcd = blk & 7;
    const int q   = blk >> 3;            // 0..255
    const int bg  = xcd * 2 + (q >> 7);
    const int row = q & 127;
    const int b   = bg >> 2, g = bg & 3;
    const int wave = tid >> 6, lane = tid & 63;
    const int lr = lane & 15;
    const int lj = lane >> 4;

    __shared__ float red[512];

    F16Frag B2[5];
    #pragma unroll
    for (int s = 0; s < 5; ++s) B2[s].q = frags2[(g * 5 + s) * 64 + lane];
    const float cbias = dcn_b[g * CG + lr];

    const _Float16* xtb = xt + (size_t)b * HW * 64;
    const _Float16* xg  = xtb + g * CG + (lj & 1) * 8;
    const uint* omw = (const uint*)om16;

    // ---- prefetch om for both tiles ----
    const int pbase = (bg << 14) + row * WW + wave * 32 + lr;
    uint     yxv[2][5];
    _Float16 mv [2][5];
    #pragma unroll
    for (int t = 0; t < 2; ++t) {
        const int p = pbase + t * 16;
        #pragma unroll
        for (int s = 0; s < 5; ++s) {
            const int kp = 2 * s + (lj >> 1);
            const int kc = (kp < 9) ? kp : 8;
            yxv[t][s] = omw[(size_t)p * 14 + kc];
            mv [t][s] = om16[(size_t)p * 28 + 18 + kc];
        }
    }

    float gs = 0.0f, gss = 0.0f;

    #pragma unroll
    for (int t = 0; t < 2; ++t) {
        const int col0 = wave * 32 + t * 16;
        const int pix0 = row * WW + col0;

        f32x4 C2 = {cbias, cbias, cbias, cbias};
        #pragma unroll
        for (int s = 0; s < 5; ++s) {
            const int  kp  = 2 * s + (lj >> 1);
            const bool kok = (kp < 9);
            const int  kc  = kok ? kp : 8;

            YX yx; yx.u = yxv[t][s];
            const float offy = (float)yx.h2[0];
            const float offx = (float)yx.h2[1];
            const float m    = kok ? (float)mv[t][s] : 0.0f;

            const float py = (float)(row       - PAD + kc / 3) + offy;
            const float px = (float)(col0 + lr - PAD + kc % 3) + offx;

            const float y0f = floorf(py), x0f = floorf(px);
            const int   y0  = (int)y0f,   x0  = (int)x0f;
            const float wy1 = py - y0f,   wx1 = px - x0f;
            const float wy0 = 1.0f - wy1, wx0 = 1.0f - wx1;
            const bool vy0 = (y0 >= 0)  & (y0 <  HH);
            const bool vy1 = (y0 >= -1) & (y0 <  HH - 1);
            const bool vx0 = (x0 >= 0)  & (x0 <  WW);
            const bool vx1 = (x0 >= -1) & (x0 <  WW - 1);
            const int yi0 = min(max(y0,     0), HH - 1);
            const int yi1 = min(max(y0 + 1, 0), HH - 1);
            const int xi0 = min(max(x0,     0), WW - 1);
            const int xi1 = min(max(x0 + 1, 0), WW - 1);
            const float my0 = wy0 * m, my1 = wy1 * m;
            const float w00 = (vy0 & vx0) ? my0 * wx0 : 0.0f;
            const float w01 = (vy0 & vx1) ? my0 * wx1 : 0.0f;
            const float w10 = (vy1 & vx0) ? my1 * wx0 : 0.0f;
            const float w11 = (vy1 & vx1) ? my1 * wx1 : 0.0f;

            F16Frag t00, t01, t10, t11;
            t00.q = *(const uint4*)(xg + (size_t)(yi0 * WW + xi0) * 64);
            t01.q = *(const uint4*)(xg + (size_t)(yi0 * WW + xi1) * 64);
            t10.q = *(const uint4*)(xg + (size_t)(yi1 * WW + xi0) * 64);
            t11.q = *(const uint4*)(xg + (size_t)(yi1 * WW + xi1) * 64);

            const _Float16 h00 = (_Float16)w00, h01 = (_Float16)w01;
            const _Float16 h10 = (_Float16)w10, h11 = (_Float16)w11;
            const f16x2 W00 = {h00, h00}, W01 = {h01, h01};
            const f16x2 W10 = {h10, h10}, W11 = {h11, h11};

            F16Frag A;
            #pragma unroll
            for (int d = 0; d < 4; ++d) {
                f16x2 acc = t00.p[d] * W00;
                acc += t01.p[d] * W01;
                acc += t10.p[d] * W10;
                acc += t11.p[d] * W11;
                A.p[d] = acc;
            }
            C2 = __builtin_amdgcn_mfma_f32_16x16x32_f16(A.f, B2[s].f, C2, 0, 0, 0);
        }

        float4 st;
        #pragma unroll
        for (int r = 0; r < 4; ++r) {
            const float v = C2[r];
            gs += v; gss += v * v;
            (&st.x)[r] = v;
        }
        *(float4*)(out + ((size_t)b * 64 + g * CG + lr) * HW + pix0 + lj * 4) = st;
    }

    red[tid] = gs; red[256 + tid] = gss;
    __syncthreads();
    for (int st2 = 128; st2 > 0; st2 >>= 1) {
        if (tid < st2) {
            red[tid]       += red[tid + st2];
            red[256 + tid] += red[256 + tid + st2];
        }
        __syncthreads();
    }
    if (tid == 0) {
        partials[(bg * 128 + row) * 2]     = red[0];
        partials[(bg * 128 + row) * 2 + 1] = red[256];
    }
}

// ---- gn_gelu2: fused GN-finalize + apply + exact GELU -----------------------
// 4096 blocks; each block covers 256 float4 of ONE channel -> one bg. It
// reduces that bg's 256 partial floats itself (parity-preserving tree).
__global__ __launch_bounds__(256) void gn_gelu2(float* __restrict__ out,
                                                const float* __restrict__ partials,
                                                const float* __restrict__ gn_w,
                                                const float* __restrict__ gn_b)
{
    const int blk = blockIdx.x;
    const int tid = threadIdx.x;
    const int bc  = blk >> 4;            // 16 blocks per (b,c)
    const int c   = bc & 63;
    const int bg  = ((bc >> 6) << 2) + (c >> 4);

    __shared__ float ls[256];
    ls[tid] = partials[bg * 256 + tid];
    __syncthreads();
    #pragma unroll
    for (int st = 128; st >= 2; st >>= 1) {      // even strides preserve parity
        if (tid < st) ls[tid] += ls[tid + st];
        __syncthreads();
    }
    const float n  = (float)(CG * HW);
    const float mu = ls[0] / n;
    const float rs = rsqrtf(ls[1] / n - mu * mu + 1e-5f);
    const float sw = gn_w[c] * rs;
    const float sb = gn_b[c] - mu * sw;

    const int idx = blk * 256 + tid;
    float4 v = ((const float4*)out)[idx];
    float rr[4] = {v.x, v.y, v.z, v.w};
    #pragma unroll
    for (int jj = 0; jj < 4; ++jj) {
        const float t = rr[jj] * sw + sb;
        rr[jj] = t * 0.5f * (1.0f + erff(t * 0.70710678118654752f));
    }
    ((float4*)out)[idx] = make_float4(rr[0], rr[1], rr[2], rr[3]);
}

// ============================ FALLBACK PATH (R7-proven) ======================

__global__ __launch_bounds__(256) void transpose_pack(const float* __restrict__ x,
                                                      _Float16* __restrict__ xt)
{
    const int t   = blockIdx.x * 256 + threadIdx.x;
    const int qq  = t & 3;
    const int p2  = t >> 2;
    const int pix = p2 & (HW - 1);
    const int b   = p2 >> 14;
    const float* xs = x + ((size_t)b * C_IN + qq * 16) * HW + pix;
    F16Frag f0, f1;
    #pragma unroll
    for (int j = 0; j < 8; ++j) f0.h[j] = (_Float16)xs[(size_t)j * HW];
    #pragma unroll
    for (int j = 0; j < 8; ++j) f1.h[j] = (_Float16)xs[(size_t)(8 + j) * HW];
    uint4* dst = (uint4*)(xt + ((size_t)b * HW + pix) * 64 + qq * 16);
    dst[0] = f0.q;
    dst[1] = f1.q;
}

__global__ __launch_bounds__(256, 4) void dcn_fused_fb(
    const _Float16* __restrict__ xt,
    const float* __restrict__ w_om,
    const float* __restrict__ b_om,
    const float* __restrict__ dcn_w,
    const float* __restrict__ dcn_b,
    const float* __restrict__ offset_scale,
    float* __restrict__ out,
    float* __restrict__ partials)
{
    const int tid = threadIdx.x;
    const int blk = blockIdx.x;
    const int xcd = blk & 7;
    const int q   = blk >> 3;
    const int bg  = xcd * 2 + (q >> 6);
    const int tb  = q & 63;
    const int b   = bg >> 2, g = bg & 3;
    const int wave = tid >> 6, lane = tid & 63;
    const int lr = lane & 15, lj = lane >> 4;

    __shared__ float om_lds[4][16][33];
    __shared__ float red[512];

    F16Frag B1[2][2];
    #pragma unroll
    for (int s = 0; s < 2; ++s)
    #pragma unroll
    for (int nt = 0; nt < 2; ++nt) {
        const int o = nt * 16 + lr;
        if (o < 27) {
            const float* src = w_om + (size_t)(g * 27 + o) * C_IN + s * 32 + lj * 8;
            #pragma unroll
            for (int e = 0; e < 8; ++e) B1[s][nt].h[e] = (_Float16)src[e];
        } else {
            #pragma unroll
            for (int e = 0; e < 4; ++e) B1[s][nt].w[e] = 0u;
        }
    }
    F16Frag B2[5];
    #pragma unroll
    for (int s = 0; s < 5; ++s) {
        const int kp  = 2 * s + (lj >> 1);
        const int cib = (lj & 1) * 8;
        if (kp < 9) {
            const float* src = dcn_w + ((size_t)(g * CG + lr) * CG + cib) * 9 + kp;
            #pragma unroll
            for (int e = 0; e < 8; ++e) B2[s].h[e] = (_Float16)src[(size_t)e * 9];
        } else {
            #pragma unroll
            for (int e = 0; e < 4; ++e) B2[s].w[e] = 0u;
        }
    }

    const float scale = offset_scale[0];
    const float bo0   = b_om[g * 27 + lr];
    const float bo1   = (lr < 11) ? b_om[g * 27 + 16 + lr] : 0.0f;
    const float cbias = dcn_b[g * CG + lr];

    const _Float16* xtb = xt + (size_t)b * HW * 64;
    const _Float16* xg  = xtb + g * CG + (lj & 1) * 8;
    float gs = 0.0f, gss = 0.0f;

    for (int t = 0; t < 4; ++t) {
        const int pix0 = tb * 256 + wave * 64 + t * 16;
        const int row  = pix0 >> 7;
        const int col0 = pix0 & 127;

        f32x4 C0 = {0, 0, 0, 0}, C1 = {0, 0, 0, 0};
        #pragma unroll
        for (int s = 0; s < 2; ++s) {
            F16Frag A;
            A.q = *(const uint4*)(xtb + (size_t)(pix0 + lr) * 64 + s * 32 + lj * 8);
            C0 = __builtin_amdgcn_mfma_f32_16x16x32_f16(A.f, B1[s][0].f, C0, 0, 0, 0);
            C1 = __builtin_amdgcn_mfma_f32_16x16x32_f16(A.f, B1[s][1].f, C1, 0, 0, 0);
        }
        #pragma unroll
        for (int r = 0; r < 4; ++r) {
            const int prow = lj * 4 + r;
            om_lds[wave][prow][lr] = (C0[r] + bo0) * scale;
            const float v1 = C1[r] + bo1;
            const int o1 = 16 + lr;
            om_lds[wave][prow][o1] = (o1 < 18) ? v1 * scale
                                   : 1.0f / (1.0f + __expf(-v1));
        }

        f32x4 C2 = {cbias, cbias, cbias, cbias};
        #pragma unroll
        for (int s = 0; s < 5; ++s) {
            const int  kp  = 2 * s + (lj >> 1);
            const bool kok = (kp < 9);
            const int  kc  = kok ? kp : 8;
            const float offy = om_lds[wave][lr][2 * kc];
            const float offx = om_lds[wave][lr][2 * kc + 1];
            const float m    = kok ? om_lds[wave][lr][18 + kc] : 0.0f;
            const float py = (float)(row  - PAD + kc / 3) + offy;
            const float px = (float)(col0 + lr - PAD + kc % 3) + offx;

            const float y0f = floorf(py), x0f = floorf(px);
            const int   y0  = (int)y0f,   x0  = (int)x0f;
            const float wy1 = py - y0f,   wx1 = px - x0f;
            const float wy0 = 1.0f - wy1, wx0 = 1.0f - wx1;
            const bool vy0 = (y0 >= 0)  & (y0 <  HH);
            const bool vy1 = (y0 >= -1) & (y0 <  HH - 1);
            const bool vx0 = (x0 >= 0)  & (x0 <  WW);
            const bool vx1 = (x0 >= -1) & (x0 <  WW - 1);
            const int yi0 = min(max(y0,     0), HH - 1);
            const int yi1 = min(max(y0 + 1, 0), HH - 1);
            const int xi0 = min(max(x0,     0), WW - 1);
            const int xi1 = min(max(x0 + 1, 0), WW - 1);
            const float my0 = wy0 * m, my1 = wy1 * m;
            const float w00 = (vy0 & vx0) ? my0 * wx0 : 0.0f;
            const float w01 = (vy0 & vx1) ? my0 * wx1 : 0.0f;
            const float w10 = (vy1 & vx0) ? my1 * wx0 : 0.0f;
            const float w11 = (vy1 & vx1) ? my1 * wx1 : 0.0f;

            F16Frag t00, t01, t10, t11;
            t00.q = *(const uint4*)(xg + (size_t)(yi0 * WW + xi0) * 64);
            t01.q = *(const uint4*)(xg + (size_t)(yi0 * WW + xi1) * 64);
            t10.q = *(const uint4*)(xg + (size_t)(yi1 * WW + xi0) * 64);
            t11.q = *(const uint4*)(xg + (size_t)(yi1 * WW + xi1) * 64);

            const _Float16 h00 = (_Float16)w00, h01 = (_Float16)w01;
            const _Float16 h10 = (_Float16)w10, h11 = (_Float16)w11;
            const f16x2 W00 = {h00, h00}, W01 = {h01, h01};
            const f16x2 W10 = {h10, h10}, W11 = {h11, h11};

            F16Frag A;
            #pragma unroll
            for (int d = 0; d < 4; ++d) {
                f16x2 acc = t00.p[d] * W00;
                acc += t01.p[d] * W01;
                acc += t10.p[d] * W10;
                acc += t11.p[d] * W11;
                A.p[d] = acc;
            }
            C2 = __builtin_amdgcn_mfma_f32_16x16x32_f16(A.f, B2[s].f, C2, 0, 0, 0);
        }

        float4 st;
        #pragma unroll
        for (int r = 0; r < 4; ++r) {
            const float v = C2[r];
            gs += v; gss += v * v;
            (&st.x)[r] = v;
        }
        *(float4*)(out + ((size_t)b * 64 + g * CG + lr) * HW + pix0 + lj * 4) = st;
    }

    red[tid] = gs; red[256 + tid] = gss;
    __syncthreads();
    for (int st2 = 128; st2 > 0; st2 >>= 1) {
        if (tid < st2) {
            red[tid]       += red[tid + st2];
            red[256 + tid] += red[256 + tid + st2];
        }
        __syncthreads();
    }
    if (tid == 0) {
        partials[(bg * 64 + tb) * 2]     = red[0];
        partials[(bg * 64 + tb) * 2 + 1] = red[256];
    }
}

__global__ __launch_bounds__(64) void gn_finalize(const float* __restrict__ partials,
                                                  float* __restrict__ stats,
                                                  int per_bg)
{
    const int bg = blockIdx.x;
    const int t  = threadIdx.x;
    float s = 0.0f, ss = 0.0f;
    for (int i = t; i < per_bg; i += 64) {
        s  += partials[(bg * per_bg + i) * 2];
        ss += partials[(bg * per_bg + i) * 2 + 1];
    }
    #pragma unroll
    for (int off = 32; off > 0; off >>= 1) {
        s  += __shfl_down(s, off);
        ss += __shfl_down(ss, off);
    }
    if (t == 0) {
        const float n   = (float)(CG * HW);
        const float mu  = s / n;
        const float var = ss / n - mu * mu;
        stats[bg * 2]     = mu;
        stats[bg * 2 + 1] = rsqrtf(var + 1e-5f);
    }
}

__global__ __launch_bounds__(256) void gn_gelu(float* __restrict__ out,
                                               const float* __restrict__ stats,
                                               const float* __restrict__ gn_w,
                                               const float* __restrict__ gn_b)
{
    const int idx = blockIdx.x * 256 + threadIdx.x;
    const int bc  = idx >> 12;
    const int c   = bc & 63;
    const int bg  = ((bc >> 6) << 2) + (c >> 4);

    const float mu = stats[bg * 2];
    const float rs = stats[bg * 2 + 1];
    const float sw = gn_w[c] * rs;
    const float sb = gn_b[c] - mu * sw;

    float4 v = ((const float4*)out)[idx];
    float rr[4] = {v.x, v.y, v.z, v.w};
    #pragma unroll
    for (int jj = 0; jj < 4; ++jj) {
        const float t = rr[jj] * sw + sb;
        rr[jj] = t * 0.5f * (1.0f + erff(t * 0.70710678118654752f));
    }
    ((float4*)out)[idx] = make_float4(rr[0], rr[1], rr[2], rr[3]);
}

// ============================ launch =========================================

extern "C" void kernel_launch(void* const* d_in, const int* in_sizes, int n_in,
                              void* d_out, int out_size, void* d_ws, size_t ws_size,
                              hipStream_t stream) {
    const float* x            = (const float*)d_in[0];
    const float* w_om         = (const float*)d_in[1];
    const float* b_om         = (const float*)d_in[2];
    const float* dcn_w        = (const float*)d_in[3];
    const float* dcn_b        = (const float*)d_in[4];
    const float* gn_w         = (const float*)d_in[5];
    const float* gn_b         = (const float*)d_in[6];
    const float* offset_scale = (const float*)d_in[7];
    float* out = (float*)d_out;
    char*  ws  = (char*)d_ws;

    _Float16* xt = (_Float16*)(ws + XT_OFF);

    if (ws_size >= NEED_BYTES) {
        _Float16* om16   = (_Float16*)(ws + OM_OFF);
        uint4* frags1    = (uint4*)(ws + FR1_OFF);
        uint4* frags2    = (uint4*)(ws + FR2_OFF);
        float* partials  = (float*)(ws + PART_OFF);

        make_frags<<<9, 256, 0, stream>>>(w_om, dcn_w, frags1, frags2);
        om_gemm_t<<<1024, 256, 0, stream>>>(x, frags1, b_om, offset_scale, xt, om16);
        dcn_sample<<<2048, 256, 0, stream>>>(xt, om16, frags2, dcn_b, out, partials);
        gn_gelu2<<<4096, 256, 0, stream>>>(out, partials, gn_w, gn_b);
    } else {
        float* partials = (float*)(ws + FB_PART_OFF);
        float* stats    = (float*)(ws + FB_STATS_OFF);
        transpose_pack<<<1024, 256, 0, stream>>>(x, xt);
        dcn_fused_fb<<<1024, 256, 0, stream>>>(xt, w_om, b_om, dcn_w, dcn_b,
                                               offset_scale, out, partials);
        gn_finalize<<<16, 64, 0, stream>>>(partials, stats, 64);
        gn_gelu<<<(BB * 64 * HW / 4) / 256, 256, 0, stream>>>(out, stats, gn_w, gn_b);
    }
}

// Round 9
// 60.314 us; speedup vs baseline: 2.0611x; 1.2044x over previous
//
#include <hip/hip_runtime.h>
#include <math.h>

#define GRP   4
#define K     9
#define PAD   1
#define C_IN  64
#define CG    16
#define HH    128
#define WW    128
#define BB    4
#define HW    (HH*WW)

typedef __attribute__((ext_vector_type(8))) _Float16 f16x8;
typedef __attribute__((ext_vector_type(2))) _Float16 f16x2;
typedef __attribute__((ext_vector_type(4))) float    f32x4;

union F16Frag { f16x8 f; _Float16 h[8]; f16x2 p[4]; uint w[4]; uint4 q; };
union YX      { uint u; f16x2 h2; };

// ---------------- ws layout --------------------------------------------------
// xt4: group-major fp16 [16 bg][HW][16ch] = 8,388,608 B (32B per pixel record)
#define XT_OFF     0
#define XT_BYTES   ((size_t)16 * HW * 16 * 2)
#define OM_OFF     XT_BYTES
#define OM_BYTES   ((size_t)16 * HW * 28 * 2)               // 14,680,064
#define FR1_OFF    (OM_OFF + OM_BYTES)
#define FR1_BYTES  (14 * 64 * 16)
#define FR2_OFF    (FR1_OFF + FR1_BYTES)
#define FR2_BYTES  (20 * 64 * 16)
#define PART_OFF   (FR2_OFF + FR2_BYTES)
#define PART_BYTES (2048 * 2 * 4)
#define STATS_OFF  (PART_OFF + PART_BYTES)
#define NEED_BYTES (STATS_OFF + 128)
// fallback path offsets (xt in [b][pix][64] layout, same byte size)
#define FB_PART_OFF  XT_BYTES
#define FB_STATS_OFF (XT_BYTES + 1024 * 2 * 4)

// ---- make_frags: precompute MFMA weight fragments ---------------------------
__global__ __launch_bounds__(256) void make_frags(const float* __restrict__ w_om,
                                                  const float* __restrict__ dcn_w,
                                                  uint4* __restrict__ frags1,
                                                  uint4* __restrict__ frags2)
{
    const int t    = blockIdx.x * 256 + threadIdx.x;
    const int lane = t & 63;
    const int lr   = lane & 15, lj = lane >> 4;
    const int f    = t >> 6;
    F16Frag r;
    #pragma unroll
    for (int e = 0; e < 4; ++e) r.w[e] = 0u;
    if (f < 14) {                          // frags1: f = nt*2+s
        const int nt = f >> 1, s = f & 1;
        const int col = nt * 16 + lr;
        const int g = col / 28, oo = col - 28 * g;
        if (oo < 27) {
            const float* src = w_om + (size_t)(g * 27 + oo) * C_IN + s * 32 + lj * 8;
            #pragma unroll
            for (int e = 0; e < 8; ++e) r.h[e] = (_Float16)src[e];
        }
        frags1[f * 64 + lane] = r.q;
    } else if (f < 34) {                   // frags2: f-14 = g*5+s
        const int f2 = f - 14;
        const int g = f2 / 5, s = f2 - 5 * g;
        const int kp = 2 * s + (lj >> 1);
        const int cib = (lj & 1) * 8;
        if (kp < 9) {
            #pragma unroll
            for (int e = 0; e < 8; ++e)
                r.h[e] = (_Float16)dcn_w[((size_t)(g * CG + lr) * CG + cib + e) * 9 + kp];
        }
        frags2[f2 * 64 + lane] = r.q;
    }
}

// ---- om_gemm_t: transpose-gather from x + om GEMM + group-major xt4 write ---
// Lane (lr,lj) holds channels lj*8..+7 (A0) and 32+lj*8..+7 (A1) of pixel
// pix0+lr. Each 8-channel slice lies in ONE group-half: A0 -> g=lj>>1,
// A1 -> g=2+(lj>>1), half=(lj&1)*8. So the xt4 write is direct.
__global__ __launch_bounds__(256, 4) void om_gemm_t(
    const float* __restrict__ x,
    const uint4* __restrict__ frags1,
    const float* __restrict__ b_om,
    const float* __restrict__ offset_scale,
    _Float16* __restrict__ xt4,
    _Float16* __restrict__ om16)
{
    const int tid  = threadIdx.x;
    const int wave = tid >> 6, lane = tid & 63;
    const int lr   = lane & 15, lj = lane >> 4;
    const int bpix0   = blockIdx.x * 64 + wave * 16;   // flat pixel over B*HW
    const int pixflat = bpix0 + lr;
    const int b       = pixflat >> 14;
    const int pixb    = pixflat & (HW - 1);
    const float scale = offset_scale[0];

    // transpose gather: 16 strided loads -> two fragments
    const float* xs = x + (size_t)b * C_IN * HW + pixb;
    F16Frag A0, A1;
    #pragma unroll
    for (int e = 0; e < 8; ++e) A0.h[e] = (_Float16)xs[(size_t)(lj * 8 + e) * HW];
    #pragma unroll
    for (int e = 0; e < 8; ++e) A1.h[e] = (_Float16)xs[(size_t)(32 + lj * 8 + e) * HW];

    // group-major xt4 write
    const int g0 = (lj >> 1), g1 = 2 + (lj >> 1);
    const int hf = (lj & 1) * 8;
    *(uint4*)(xt4 + ((size_t)(b * 4 + g0) * HW + pixb) * 16 + hf) = A0.q;
    *(uint4*)(xt4 + ((size_t)(b * 4 + g1) * HW + pixb) * 16 + hf) = A1.q;

    // per-(lane,nt) metadata
    int g_[7], oo_[7];
    float bo_[7];
    #pragma unroll
    for (int nt = 0; nt < 7; ++nt) {
        const int col = nt * 16 + lr;
        const int g = col / 28, oo = col - 28 * g;
        g_[nt] = g; oo_[nt] = oo;
        bo_[nt] = (oo < 27) ? b_om[g * 27 + oo] : 0.0f;
    }

    const int bq = bpix0 >> 14;
    const int pq = bpix0 & (HW - 1);
    #pragma unroll
    for (int nt = 0; nt < 7; ++nt) {
        F16Frag B0, B1;
        B0.q = frags1[(nt * 2 + 0) * 64 + lane];
        B1.q = frags1[(nt * 2 + 1) * 64 + lane];
        f32x4 C = {0, 0, 0, 0};
        C = __builtin_amdgcn_mfma_f32_16x16x32_f16(A0.f, B0.f, C, 0, 0, 0);
        C = __builtin_amdgcn_mfma_f32_16x16x32_f16(A1.f, B1.f, C, 0, 0, 0);
        const int g = g_[nt], oo = oo_[nt];
        if (oo < 27) {
            const size_t base = ((size_t)(bq * 4 + g) * HW + pq + lj * 4);
            #pragma unroll
            for (int r = 0; r < 4; ++r) {
                float v = C[r] + bo_[nt];
                v = (oo < 18) ? v * scale : 1.0f / (1.0f + __expf(-v));
                om16[(base + r) * 28 + oo] = (_Float16)v;
            }
        }
    }
}

// ---- dcn_sample: sampling + PV GEMM + GN partials ---------------------------
// 2048 blocks x 4 waves; block = (bg,row); wave = 32 px (2 tiles of 16).
// xt4 group-major: tap reads 16B of a 32B pixel record -> ~4 pixels per 128B
// cache line across adjacent lr lanes (was 1 pixel/line with [pix][64]).
__global__ __launch_bounds__(256, 4) void dcn_sample(
    const _Float16* __restrict__ xt4,
    const _Float16* __restrict__ om16,
    const uint4* __restrict__ frags2,
    const float* __restrict__ dcn_b,
    float* __restrict__ out,
    float* __restrict__ partials)
{
    const int tid = threadIdx.x;
    const int blk = blockIdx.x;
    const int xcd = blk & 7;
    const int q   = blk >> 3;            // 0..255
    const int bg  = xcd * 2 + (q >> 7);
    const int row = q & 127;
    const int b   = bg >> 2, g = bg & 3;
    const int wave = tid >> 6, lane = tid & 63;
    const int lr = lane & 15;
    const int lj = lane >> 4;

    __shared__ float red[512];

    F16Frag B2[5];
    #pragma unroll
    for (int s = 0; s < 5; ++s) B2[s].q = frags2[(g * 5 + s) * 64 + lane];
    const float cbias = dcn_b[g * CG + lr];

    const _Float16* xg = xt4 + (size_t)bg * HW * 16 + (lj & 1) * 8;
    const uint* omw = (const uint*)om16;

    // ---- prefetch om for both tiles ----
    const int pbase = (bg << 14) + row * WW + wave * 32 + lr;
    uint     yxv[2][5];
    _Float16 mv [2][5];
    #pragma unroll
    for (int t = 0; t < 2; ++t) {
        const int p = pbase + t * 16;
        #pragma unroll
        for (int s = 0; s < 5; ++s) {
            const int kp = 2 * s + (lj >> 1);
            const int kc = (kp < 9) ? kp : 8;
            yxv[t][s] = omw[(size_t)p * 14 + kc];
            mv [t][s] = om16[(size_t)p * 28 + 18 + kc];
        }
    }

    float gs = 0.0f, gss = 0.0f;

    #pragma unroll
    for (int t = 0; t < 2; ++t) {
        const int col0 = wave * 32 + t * 16;
        const int pix0 = row * WW + col0;

        f32x4 C2 = {cbias, cbias, cbias, cbias};
        #pragma unroll
        for (int s = 0; s < 5; ++s) {
            const int  kp  = 2 * s + (lj >> 1);
            const bool kok = (kp < 9);
            const int  kc  = kok ? kp : 8;

            YX yx; yx.u = yxv[t][s];
            const float offy = (float)yx.h2[0];
            const float offx = (float)yx.h2[1];
            const float m    = kok ? (float)mv[t][s] : 0.0f;

            const float py = (float)(row       - PAD + kc / 3) + offy;
            const float px = (float)(col0 + lr - PAD + kc % 3) + offx;

            const float y0f = floorf(py), x0f = floorf(px);
            const int   y0  = (int)y0f,   x0  = (int)x0f;
            const float wy1 = py - y0f,   wx1 = px - x0f;
            const float wy0 = 1.0f - wy1, wx0 = 1.0f - wx1;
            const bool vy0 = (y0 >= 0)  & (y0 <  HH);
            const bool vy1 = (y0 >= -1) & (y0 <  HH - 1);
            const bool vx0 = (x0 >= 0)  & (x0 <  WW);
            const bool vx1 = (x0 >= -1) & (x0 <  WW - 1);
            const int yi0 = min(max(y0,     0), HH - 1);
            const int yi1 = min(max(y0 + 1, 0), HH - 1);
            const int xi0 = min(max(x0,     0), WW - 1);
            const int xi1 = min(max(x0 + 1, 0), WW - 1);
            const float my0 = wy0 * m, my1 = wy1 * m;
            const float w00 = (vy0 & vx0) ? my0 * wx0 : 0.0f;
            const float w01 = (vy0 & vx1) ? my0 * wx1 : 0.0f;
            const float w10 = (vy1 & vx0) ? my1 * wx0 : 0.0f;
            const float w11 = (vy1 & vx1) ? my1 * wx1 : 0.0f;

            F16Frag t00, t01, t10, t11;
            t00.q = *(const uint4*)(xg + (size_t)(yi0 * WW + xi0) * 16);
            t01.q = *(const uint4*)(xg + (size_t)(yi0 * WW + xi1) * 16);
            t10.q = *(const uint4*)(xg + (size_t)(yi1 * WW + xi0) * 16);
            t11.q = *(const uint4*)(xg + (size_t)(yi1 * WW + xi1) * 16);

            const _Float16 h00 = (_Float16)w00, h01 = (_Float16)w01;
            const _Float16 h10 = (_Float16)w10, h11 = (_Float16)w11;
            const f16x2 W00 = {h00, h00}, W01 = {h01, h01};
            const f16x2 W10 = {h10, h10}, W11 = {h11, h11};

            F16Frag A;
            #pragma unroll
            for (int d = 0; d < 4; ++d) {
                f16x2 acc = t00.p[d] * W00;
                acc += t01.p[d] * W01;
                acc += t10.p[d] * W10;
                acc += t11.p[d] * W11;
                A.p[d] = acc;
            }
            C2 = __builtin_amdgcn_mfma_f32_16x16x32_f16(A.f, B2[s].f, C2, 0, 0, 0);
        }

        float4 st;
        #pragma unroll
        for (int r = 0; r < 4; ++r) {
            const float v = C2[r];
            gs += v; gss += v * v;
            (&st.x)[r] = v;
        }
        *(float4*)(out + ((size_t)b * 64 + g * CG + lr) * HW + pix0 + lj * 4) = st;
    }

    red[tid] = gs; red[256 + tid] = gss;
    __syncthreads();
    for (int st2 = 128; st2 > 0; st2 >>= 1) {
        if (tid < st2) {
            red[tid]       += red[tid + st2];
            red[256 + tid] += red[256 + tid + st2];
        }
        __syncthreads();
    }
    if (tid == 0) {
        partials[(bg * 128 + row) * 2]     = red[0];
        partials[(bg * 128 + row) * 2 + 1] = red[256];
    }
}

// ---- gn_gelu2: fused GN-finalize + apply + exact GELU -----------------------
__global__ __launch_bounds__(256) void gn_gelu2(float* __restrict__ out,
                                                const float* __restrict__ partials,
                                                const float* __restrict__ gn_w,
                                                const float* __restrict__ gn_b)
{
    const int blk = blockIdx.x;
    const int tid = threadIdx.x;
    const int bc  = blk >> 4;            // 16 blocks per (b,c)
    const int c   = bc & 63;
    const int bg  = ((bc >> 6) << 2) + (c >> 4);

    __shared__ float ls[256];
    ls[tid] = partials[bg * 256 + tid];
    __syncthreads();
    #pragma unroll
    for (int st = 128; st >= 2; st >>= 1) {      // even strides preserve parity
        if (tid < st) ls[tid] += ls[tid + st];
        __syncthreads();
    }
    const float n  = (float)(CG * HW);
    const float mu = ls[0] / n;
    const float rs = rsqrtf(ls[1] / n - mu * mu + 1e-5f);
    const float sw = gn_w[c] * rs;
    const float sb = gn_b[c] - mu * sw;

    const int idx = blk * 256 + tid;
    float4 v = ((const float4*)out)[idx];
    float rr[4] = {v.x, v.y, v.z, v.w};
    #pragma unroll
    for (int jj = 0; jj < 4; ++jj) {
        const float t = rr[jj] * sw + sb;
        rr[jj] = t * 0.5f * (1.0f + erff(t * 0.70710678118654752f));
    }
    ((float4*)out)[idx] = make_float4(rr[0], rr[1], rr[2], rr[3]);
}

// ============================ FALLBACK PATH (R7-proven, [pix][64] layout) ====

__global__ __launch_bounds__(256) void transpose_pack(const float* __restrict__ x,
                                                      _Float16* __restrict__ xt)
{
    const int t   = blockIdx.x * 256 + threadIdx.x;
    const int qq  = t & 3;
    const int p2  = t >> 2;
    const int pix = p2 & (HW - 1);
    const int b   = p2 >> 14;
    const float* xs = x + ((size_t)b * C_IN + qq * 16) * HW + pix;
    F16Frag f0, f1;
    #pragma unroll
    for (int j = 0; j < 8; ++j) f0.h[j] = (_Float16)xs[(size_t)j * HW];
    #pragma unroll
    for (int j = 0; j < 8; ++j) f1.h[j] = (_Float16)xs[(size_t)(8 + j) * HW];
    uint4* dst = (uint4*)(xt + ((size_t)b * HW + pix) * 64 + qq * 16);
    dst[0] = f0.q;
    dst[1] = f1.q;
}

__global__ __launch_bounds__(256, 4) void dcn_fused_fb(
    const _Float16* __restrict__ xt,
    const float* __restrict__ w_om,
    const float* __restrict__ b_om,
    const float* __restrict__ dcn_w,
    const float* __restrict__ dcn_b,
    const float* __restrict__ offset_scale,
    float* __restrict__ out,
    float* __restrict__ partials)
{
    const int tid = threadIdx.x;
    const int blk = blockIdx.x;
    const int xcd = blk & 7;
    const int q   = blk >> 3;
    const int bg  = xcd * 2 + (q >> 6);
    const int tb  = q & 63;
    const int b   = bg >> 2, g = bg & 3;
    const int wave = tid >> 6, lane = tid & 63;
    const int lr = lane & 15, lj = lane >> 4;

    __shared__ float om_lds[4][16][33];
    __shared__ float red[512];

    F16Frag B1[2][2];
    #pragma unroll
    for (int s = 0; s < 2; ++s)
    #pragma unroll
    for (int nt = 0; nt < 2; ++nt) {
        const int o = nt * 16 + lr;
        if (o < 27) {
            const float* src = w_om + (size_t)(g * 27 + o) * C_IN + s * 32 + lj * 8;
            #pragma unroll
            for (int e = 0; e < 8; ++e) B1[s][nt].h[e] = (_Float16)src[e];
        } else {
            #pragma unroll
            for (int e = 0; e < 4; ++e) B1[s][nt].w[e] = 0u;
        }
    }
    F16Frag B2[5];
    #pragma unroll
    for (int s = 0; s < 5; ++s) {
        const int kp  = 2 * s + (lj >> 1);
        const int cib = (lj & 1) * 8;
        if (kp < 9) {
            const float* src = dcn_w + ((size_t)(g * CG + lr) * CG + cib) * 9 + kp;
            #pragma unroll
            for (int e = 0; e < 8; ++e) B2[s].h[e] = (_Float16)src[(size_t)e * 9];
        } else {
            #pragma unroll
            for (int e = 0; e < 4; ++e) B2[s].w[e] = 0u;
        }
    }

    const float scale = offset_scale[0];
    const float bo0   = b_om[g * 27 + lr];
    const float bo1   = (lr < 11) ? b_om[g * 27 + 16 + lr] : 0.0f;
    const float cbias = dcn_b[g * CG + lr];

    const _Float16* xtb = xt + (size_t)b * HW * 64;
    const _Float16* xg  = xtb + g * CG + (lj & 1) * 8;
    float gs = 0.0f, gss = 0.0f;

    for (int t = 0; t < 4; ++t) {
        const int pix0 = tb * 256 + wave * 64 + t * 16;
        const int row  = pix0 >> 7;
        const int col0 = pix0 & 127;

        f32x4 C0 = {0, 0, 0, 0}, C1 = {0, 0, 0, 0};
        #pragma unroll
        for (int s = 0; s < 2; ++s) {
            F16Frag A;
            A.q = *(const uint4*)(xtb + (size_t)(pix0 + lr) * 64 + s * 32 + lj * 8);
            C0 = __builtin_amdgcn_mfma_f32_16x16x32_f16(A.f, B1[s][0].f, C0, 0, 0, 0);
            C1 = __builtin_amdgcn_mfma_f32_16x16x32_f16(A.f, B1[s][1].f, C1, 0, 0, 0);
        }
        #pragma unroll
        for (int r = 0; r < 4; ++r) {
            const int prow = lj * 4 + r;
            om_lds[wave][prow][lr] = (C0[r] + bo0) * scale;
            const float v1 = C1[r] + bo1;
            const int o1 = 16 + lr;
            om_lds[wave][prow][o1] = (o1 < 18) ? v1 * scale
                                   : 1.0f / (1.0f + __expf(-v1));
        }

        f32x4 C2 = {cbias, cbias, cbias, cbias};
        #pragma unroll
        for (int s = 0; s < 5; ++s) {
            const int  kp  = 2 * s + (lj >> 1);
            const bool kok = (kp < 9);
            const int  kc  = kok ? kp : 8;
            const float offy = om_lds[wave][lr][2 * kc];
            const float offx = om_lds[wave][lr][2 * kc + 1];
            const float m    = kok ? om_lds[wave][lr][18 + kc] : 0.0f;
            const float py = (float)(row  - PAD + kc / 3) + offy;
            const float px = (float)(col0 + lr - PAD + kc % 3) + offx;

            const float y0f = floorf(py), x0f = floorf(px);
            const int   y0  = (int)y0f,   x0  = (int)x0f;
            const float wy1 = py - y0f,   wx1 = px - x0f;
            const float wy0 = 1.0f - wy1, wx0 = 1.0f - wx1;
            const bool vy0 = (y0 >= 0)  & (y0 <  HH);
            const bool vy1 = (y0 >= -1) & (y0 <  HH - 1);
            const bool vx0 = (x0 >= 0)  & (x0 <  WW);
            const bool vx1 = (x0 >= -1) & (x0 <  WW - 1);
            const int yi0 = min(max(y0,     0), HH - 1);
            const int yi1 = min(max(y0 + 1, 0), HH - 1);
            const int xi0 = min(max(x0,     0), WW - 1);
            const int xi1 = min(max(x0 + 1, 0), WW - 1);
            const float my0 = wy0 * m, my1 = wy1 * m;
            const float w00 = (vy0 & vx0) ? my0 * wx0 : 0.0f;
            const float w01 = (vy0 & vx1) ? my0 * wx1 : 0.0f;
            const float w10 = (vy1 & vx0) ? my1 * wx0 : 0.0f;
            const float w11 = (vy1 & vx1) ? my1 * wx1 : 0.0f;

            F16Frag t00, t01, t10, t11;
            t00.q = *(const uint4*)(xg + (size_t)(yi0 * WW + xi0) * 64);
            t01.q = *(const uint4*)(xg + (size_t)(yi0 * WW + xi1) * 64);
            t10.q = *(const uint4*)(xg + (size_t)(yi1 * WW + xi0) * 64);
            t11.q = *(const uint4*)(xg + (size_t)(yi1 * WW + xi1) * 64);

            const _Float16 h00 = (_Float16)w00, h01 = (_Float16)w01;
            const _Float16 h10 = (_Float16)w10, h11 = (_Float16)w11;
            const f16x2 W00 = {h00, h00}, W01 = {h01, h01};
            const f16x2 W10 = {h10, h10}, W11 = {h11, h11};

            F16Frag A;
            #pragma unroll
            for (int d = 0; d < 4; ++d) {
                f16x2 acc = t00.p[d] * W00;
                acc += t01.p[d] * W01;
                acc += t10.p[d] * W10;
                acc += t11.p[d] * W11;
                A.p[d] = acc;
            }
            C2 = __builtin_amdgcn_mfma_f32_16x16x32_f16(A.f, B2[s].f, C2, 0, 0, 0);
        }

        float4 st;
        #pragma unroll
        for (int r = 0; r < 4; ++r) {
            const float v = C2[r];
            gs += v; gss += v * v;
            (&st.x)[r] = v;
        }
        *(float4*)(out + ((size_t)b * 64 + g * CG + lr) * HW + pix0 + lj * 4) = st;
    }

    red[tid] = gs; red[256 + tid] = gss;
    __syncthreads();
    for (int st2 = 128; st2 > 0; st2 >>= 1) {
        if (tid < st2) {
            red[tid]       += red[tid + st2];
            red[256 + tid] += red[256 + tid + st2];
        }
        __syncthreads();
    }
    if (tid == 0) {
        partials[(bg * 64 + tb) * 2]     = red[0];
        partials[(bg * 64 + tb) * 2 + 1] = red[256];
    }
}

__global__ __launch_bounds__(64) void gn_finalize(const float* __restrict__ partials,
                                                  float* __restrict__ stats,
                                                  int per_bg)
{
    const int bg = blockIdx.x;
    const int t  = threadIdx.x;
    float s = 0.0f, ss = 0.0f;
    for (int i = t; i < per_bg; i += 64) {
        s  += partials[(bg * per_bg + i) * 2];
        ss += partials[(bg * per_bg + i) * 2 + 1];
    }
    #pragma unroll
    for (int off = 32; off > 0; off >>= 1) {
        s  += __shfl_down(s, off);
        ss += __shfl_down(ss, off);
    }
    if (t == 0) {
        const float n   = (float)(CG * HW);
        const float mu  = s / n;
        const float var = ss / n - mu * mu;
        stats[bg * 2]     = mu;
        stats[bg * 2 + 1] = rsqrtf(var + 1e-5f);
    }
}

__global__ __launch_bounds__(256) void gn_gelu(float* __restrict__ out,
                                               const float* __restrict__ stats,
                                               const float* __restrict__ gn_w,
                                               const float* __restrict__ gn_b)
{
    const int idx = blockIdx.x * 256 + threadIdx.x;
    const int bc  = idx >> 12;
    const int c   = bc & 63;
    const int bg  = ((bc >> 6) << 2) + (c >> 4);

    const float mu = stats[bg * 2];
    const float rs = stats[bg * 2 + 1];
    const float sw = gn_w[c] * rs;
    const float sb = gn_b[c] - mu * sw;

    float4 v = ((const float4*)out)[idx];
    float rr[4] = {v.x, v.y, v.z, v.w};
    #pragma unroll
    for (int jj = 0; jj < 4; ++jj) {
        const float t = rr[jj] * sw + sb;
        rr[jj] = t * 0.5f * (1.0f + erff(t * 0.70710678118654752f));
    }
    ((float4*)out)[idx] = make_float4(rr[0], rr[1], rr[2], rr[3]);
}

// ============================ launch =========================================

extern "C" void kernel_launch(void* const* d_in, const int* in_sizes, int n_in,
                              void* d_out, int out_size, void* d_ws, size_t ws_size,
                              hipStream_t stream) {
    const float* x            = (const float*)d_in[0];
    const float* w_om         = (const float*)d_in[1];
    const float* b_om         = (const float*)d_in[2];
    const float* dcn_w        = (const float*)d_in[3];
    const float* dcn_b        = (const float*)d_in[4];
    const float* gn_w         = (const float*)d_in[5];
    const float* gn_b         = (const float*)d_in[6];
    const float* offset_scale = (const float*)d_in[7];
    float* out = (float*)d_out;
    char*  ws  = (char*)d_ws;

    _Float16* xt = (_Float16*)(ws + XT_OFF);

    if (ws_size >= NEED_BYTES) {
        _Float16* om16   = (_Float16*)(ws + OM_OFF);
        uint4* frags1    = (uint4*)(ws + FR1_OFF);
        uint4* frags2    = (uint4*)(ws + FR2_OFF);
        float* partials  = (float*)(ws + PART_OFF);

        make_frags<<<9, 256, 0, stream>>>(w_om, dcn_w, frags1, frags2);
        om_gemm_t<<<1024, 256, 0, stream>>>(x, frags1, b_om, offset_scale, xt, om16);
        dcn_sample<<<2048, 256, 0, stream>>>(xt, om16, frags2, dcn_b, out, partials);
        gn_gelu2<<<4096, 256, 0, stream>>>(out, partials, gn_w, gn_b);
    } else {
        float* partials = (float*)(ws + FB_PART_OFF);
        float* stats    = (float*)(ws + FB_STATS_OFF);
        transpose_pack<<<1024, 256, 0, stream>>>(x, xt);
        dcn_fused_fb<<<1024, 256, 0, stream>>>(xt, w_om, b_om, dcn_w, dcn_b,
                                               offset_scale, out, partials);
        gn_finalize<<<16, 64, 0, stream>>>(partials, stats, 64);
        gn_gelu<<<(BB * 64 * HW / 4) / 256, 256, 0, stream>>>(out, stats, gn_w, gn_b);
    }
}

// Round 10
// 54.927 us; speedup vs baseline: 2.2632x; 1.0981x over previous
//
#include <hip/hip_runtime.h>
#include <math.h>

#define GRP   4
#define K     9
#define PAD   1
#define C_IN  64
#define CG    16
#define HH    128
#define WW    128
#define BB    4
#define HW    (HH*WW)

typedef __attribute__((ext_vector_type(8))) _Float16 f16x8;
typedef __attribute__((ext_vector_type(2))) _Float16 f16x2;
typedef __attribute__((ext_vector_type(4))) float    f32x4;

union F16Frag { f16x8 f; _Float16 h[8]; f16x2 p[4]; uint w[4]; uint4 q; };
union YX      { uint u; f16x2 h2; };

// ---------------- ws layout --------------------------------------------------
// xt4 group-major fp16 [16 bg][HW][16ch] | om_yx uint planes [9][16*HW] |
// om_m half planes [9][16*HW] | frags | partials
#define PLANE      ((size_t)16 * HW)                        // 262,144
#define XT_OFF     0
#define XT_BYTES   ((size_t)16 * HW * 16 * 2)               // 8,388,608
#define OMYX_OFF   XT_BYTES
#define OMYX_BYTES (9 * PLANE * 4)                          // 9,437,184
#define OMM_OFF    (OMYX_OFF + OMYX_BYTES)
#define OMM_BYTES  (9 * PLANE * 2)                          // 4,718,592
#define FR1_OFF    (OMM_OFF + OMM_BYTES)
#define FR1_BYTES  (14 * 64 * 16)
#define FR2_OFF    (FR1_OFF + FR1_BYTES)
#define FR2_BYTES  (20 * 64 * 16)
#define PART_OFF   (FR2_OFF + FR2_BYTES)
#define PART_BYTES (2048 * 2 * 4)
#define NEED_BYTES (PART_OFF + PART_BYTES + 128)
// fallback path offsets ([pix][64] xt layout, R7-proven)
#define FB_PART_OFF  XT_BYTES
#define FB_STATS_OFF (XT_BYTES + 1024 * 2 * 4)

// ---- make_frags: precompute MFMA weight fragments ---------------------------
__global__ __launch_bounds__(256) void make_frags(const float* __restrict__ w_om,
                                                  const float* __restrict__ dcn_w,
                                                  uint4* __restrict__ frags1,
                                                  uint4* __restrict__ frags2)
{
    const int t    = blockIdx.x * 256 + threadIdx.x;
    const int lane = t & 63;
    const int lr   = lane & 15, lj = lane >> 4;
    const int f    = t >> 6;
    F16Frag r;
    #pragma unroll
    for (int e = 0; e < 4; ++e) r.w[e] = 0u;
    if (f < 14) {                          // frags1: f = nt*2+s
        const int nt = f >> 1, s = f & 1;
        const int col = nt * 16 + lr;
        const int g = col / 28, oo = col - 28 * g;
        if (oo < 27) {
            const float* src = w_om + (size_t)(g * 27 + oo) * C_IN + s * 32 + lj * 8;
            #pragma unroll
            for (int e = 0; e < 8; ++e) r.h[e] = (_Float16)src[e];
        }
        frags1[f * 64 + lane] = r.q;
    } else if (f < 34) {                   // frags2: f-14 = g*5+s
        const int f2 = f - 14;
        const int g = f2 / 5, s = f2 - 5 * g;
        const int kp = 2 * s + (lj >> 1);
        const int cib = (lj & 1) * 8;
        if (kp < 9) {
            #pragma unroll
            for (int e = 0; e < 8; ++e)
                r.h[e] = (_Float16)dcn_w[((size_t)(g * CG + lr) * CG + cib + e) * 9 + kp];
        }
        frags2[f2 * 64 + lane] = r.q;
    }
}

// ---- om_gemm_t: transpose-gather + om GEMM -> planar om, group-major xt4 ----
__global__ __launch_bounds__(256, 4) void om_gemm_t(
    const float* __restrict__ x,
    const uint4* __restrict__ frags1,
    const float* __restrict__ b_om,
    const float* __restrict__ offset_scale,
    _Float16* __restrict__ xt4,
    _Float16* __restrict__ om_yx,     // [9][PLANE] interleaved y,x (2 halfs)
    _Float16* __restrict__ om_m)      // [9][PLANE]
{
    const int tid  = threadIdx.x;
    const int wave = tid >> 6, lane = tid & 63;
    const int lr   = lane & 15, lj = lane >> 4;
    const int bpix0   = blockIdx.x * 64 + wave * 16;   // flat pixel over B*HW
    const int pixflat = bpix0 + lr;
    const int b       = pixflat >> 14;
    const int pixb    = pixflat & (HW - 1);
    const float scale = offset_scale[0];

    // transpose gather: 16 strided loads -> two fragments
    const float* xs = x + (size_t)b * C_IN * HW + pixb;
    F16Frag A0, A1;
    #pragma unroll
    for (int e = 0; e < 8; ++e) A0.h[e] = (_Float16)xs[(size_t)(lj * 8 + e) * HW];
    #pragma unroll
    for (int e = 0; e < 8; ++e) A1.h[e] = (_Float16)xs[(size_t)(32 + lj * 8 + e) * HW];

    // group-major xt4 write (A0 -> g=lj>>1, A1 -> g=2+(lj>>1), half=(lj&1)*8)
    const int g0 = (lj >> 1), g1 = 2 + (lj >> 1);
    const int hf = (lj & 1) * 8;
    *(uint4*)(xt4 + ((size_t)(b * 4 + g0) * HW + pixb) * 16 + hf) = A0.q;
    *(uint4*)(xt4 + ((size_t)(b * 4 + g1) * HW + pixb) * 16 + hf) = A1.q;

    // per-(lane,nt) metadata
    int g_[7], oo_[7];
    float bo_[7];
    #pragma unroll
    for (int nt = 0; nt < 7; ++nt) {
        const int col = nt * 16 + lr;
        const int g = col / 28, oo = col - 28 * g;
        g_[nt] = g; oo_[nt] = oo;
        bo_[nt] = (oo < 27) ? b_om[g * 27 + oo] : 0.0f;
    }

    const int bq = bpix0 >> 14;
    const int pq = bpix0 & (HW - 1);
    #pragma unroll
    for (int nt = 0; nt < 7; ++nt) {
        F16Frag B0, B1;
        B0.q = frags1[(nt * 2 + 0) * 64 + lane];
        B1.q = frags1[(nt * 2 + 1) * 64 + lane];
        f32x4 C = {0, 0, 0, 0};
        C = __builtin_amdgcn_mfma_f32_16x16x32_f16(A0.f, B0.f, C, 0, 0, 0);
        C = __builtin_amdgcn_mfma_f32_16x16x32_f16(A1.f, B1.f, C, 0, 0, 0);
        const int g = g_[nt], oo = oo_[nt];
        if (oo < 27) {
            const size_t base = ((size_t)(bq * 4 + g) * HW + pq + lj * 4);
            if (oo < 18) {
                const int k = oo >> 1, comp = oo & 1;
                #pragma unroll
                for (int r = 0; r < 4; ++r)
                    om_yx[((size_t)k * PLANE + base + r) * 2 + comp] =
                        (_Float16)((C[r] + bo_[nt]) * scale);
            } else {
                const int k = oo - 18;
                #pragma unroll
                for (int r = 0; r < 4; ++r)
                    om_m[(size_t)k * PLANE + base + r] =
                        (_Float16)(1.0f / (1.0f + __expf(-(C[r] + bo_[nt]))));
            }
        }
    }
}

// ---- dcn_sample: LDS-staged sampling + PV GEMM + GN partials ----------------
// 2048 blocks x 4 waves; block = (bg,row). Stage rows wr0..wr0+5 of this bg's
// xt4 plane into LDS as [row][half][xi] (16B records -> 2-way bank = free).
// Taps read LDS; rare out-of-window lanes take a divergent global fixup.
__global__ __launch_bounds__(256, 4) void dcn_sample(
    const _Float16* __restrict__ xt4,
    const uint* __restrict__ om_yx_u,
    const _Float16* __restrict__ om_m,
    const uint4* __restrict__ frags2,
    const float* __restrict__ dcn_b,
    float* __restrict__ out,
    float* __restrict__ partials)
{
    const int tid = threadIdx.x;
    const int blk = blockIdx.x;
    const int xcd = blk & 7;
    const int q   = blk >> 3;            // 0..255
    const int bg  = xcd * 2 + (q >> 7);
    const int row = q & 127;
    const int b   = bg >> 2, g = bg & 3;
    const int wave = tid >> 6, lane = tid & 63;
    const int lr = lane & 15;
    const int lj = lane >> 4;
    const int hsel = lj & 1;

    __shared__ uint4 sm4[1536];          // 6 rows x [half][128 xi] x 16B
    __shared__ float red[512];

    // ---- stage window rows wr0..wr0+5 ----
    const int wr0 = min(max(row - 2, 0), HH - 6);
    {
        const uint4* src = (const uint4*)(xt4 + ((size_t)bg * HW + wr0 * WW) * 16);
        #pragma unroll
        for (int i = tid; i < 1536; i += 256) {
            // src idx i: rec=i>>1 (row r=rec>>7, xi=rec&127), half=i&1
            const int dst = ((i >> 8) * 2 + (i & 1)) * 128 + ((i >> 1) & 127);
            sm4[dst] = src[i];
        }
    }

    F16Frag B2[5];
    #pragma unroll
    for (int s = 0; s < 5; ++s) B2[s].q = frags2[(g * 5 + s) * 64 + lane];
    const float cbias = dcn_b[g * CG + lr];

    // ---- coalesced planar om prefetch for both tiles ----
    const int pbase = (bg << 14) + row * WW + wave * 32 + lr;
    uint     yxv[2][5];
    _Float16 mv [2][5];
    #pragma unroll
    for (int t = 0; t < 2; ++t) {
        const int p = pbase + t * 16;
        #pragma unroll
        for (int s = 0; s < 5; ++s) {
            const int kp = 2 * s + (lj >> 1);
            const int kc = (kp < 9) ? kp : 8;
            yxv[t][s] = om_yx_u[(size_t)kc * PLANE + p];
            mv [t][s] = om_m  [(size_t)kc * PLANE + p];
        }
    }

    __syncthreads();
    const _Float16* smh = (const _Float16*)sm4;
    const _Float16* xgf = xt4 + (size_t)bg * HW * 16 + hsel * 8;

    float gs = 0.0f, gss = 0.0f;

    #pragma unroll
    for (int t = 0; t < 2; ++t) {
        const int col0 = wave * 32 + t * 16;
        const int pix0 = row * WW + col0;

        f32x4 C2 = {cbias, cbias, cbias, cbias};
        #pragma unroll
        for (int s = 0; s < 5; ++s) {
            const int  kp  = 2 * s + (lj >> 1);
            const bool kok = (kp < 9);
            const int  kc  = kok ? kp : 8;

            YX yx; yx.u = yxv[t][s];
            const float offy = (float)yx.h2[0];
            const float offx = (float)yx.h2[1];
            const float m    = kok ? (float)mv[t][s] : 0.0f;

            const float py = (float)(row       - PAD + kc / 3) + offy;
            const float px = (float)(col0 + lr - PAD + kc % 3) + offx;

            const float y0f = floorf(py), x0f = floorf(px);
            const int   y0  = (int)y0f,   x0  = (int)x0f;
            const float wy1 = py - y0f,   wx1 = px - x0f;
            const float wy0 = 1.0f - wy1, wx0 = 1.0f - wx1;
            const bool vy0 = (y0 >= 0)  & (y0 <  HH);
            const bool vy1 = (y0 >= -1) & (y0 <  HH - 1);
            const bool vx0 = (x0 >= 0)  & (x0 <  WW);
            const bool vx1 = (x0 >= -1) & (x0 <  WW - 1);
            const int yi0 = min(max(y0,     0), HH - 1);
            const int yi1 = min(max(y0 + 1, 0), HH - 1);
            const int xi0 = min(max(x0,     0), WW - 1);
            const int xi1 = min(max(x0 + 1, 0), WW - 1);
            const float my0 = wy0 * m, my1 = wy1 * m;
            const float w00 = (vy0 & vx0) ? my0 * wx0 : 0.0f;
            const float w01 = (vy0 & vx1) ? my0 * wx1 : 0.0f;
            const float w10 = (vy1 & vx0) ? my1 * wx0 : 0.0f;
            const float w11 = (vy1 & vx1) ? my1 * wx1 : 0.0f;

            // LDS tap reads (window-clamped); fixup below for misses
            const int ly0 = yi0 - wr0, ly1 = yi1 - wr0;
            const bool okw = (ly0 >= 0) & (ly1 <= 5);
            const int cy0 = min(max(ly0, 0), 5);
            const int cy1 = min(max(ly1, 0), 5);
            const int r0 = (cy0 * 2 + hsel) * 128;
            const int r1 = (cy1 * 2 + hsel) * 128;

            F16Frag t00, t01, t10, t11;
            t00.q = *(const uint4*)(smh + (size_t)(r0 + xi0) * 8);
            t01.q = *(const uint4*)(smh + (size_t)(r0 + xi1) * 8);
            t10.q = *(const uint4*)(smh + (size_t)(r1 + xi0) * 8);
            t11.q = *(const uint4*)(smh + (size_t)(r1 + xi1) * 8);
            if (!okw) {   // rare: offsets beyond staged window
                t00.q = *(const uint4*)(xgf + (size_t)(yi0 * WW + xi0) * 16);
                t01.q = *(const uint4*)(xgf + (size_t)(yi0 * WW + xi1) * 16);
                t10.q = *(const uint4*)(xgf + (size_t)(yi1 * WW + xi0) * 16);
                t11.q = *(const uint4*)(xgf + (size_t)(yi1 * WW + xi1) * 16);
            }

            const _Float16 h00 = (_Float16)w00, h01 = (_Float16)w01;
            const _Float16 h10 = (_Float16)w10, h11 = (_Float16)w11;
            const f16x2 W00 = {h00, h00}, W01 = {h01, h01};
            const f16x2 W10 = {h10, h10}, W11 = {h11, h11};

            F16Frag A;
            #pragma unroll
            for (int d = 0; d < 4; ++d) {
                f16x2 acc = t00.p[d] * W00;
                acc += t01.p[d] * W01;
                acc += t10.p[d] * W10;
                acc += t11.p[d] * W11;
                A.p[d] = acc;
            }
            C2 = __builtin_amdgcn_mfma_f32_16x16x32_f16(A.f, B2[s].f, C2, 0, 0, 0);
        }

        float4 st;
        #pragma unroll
        for (int r = 0; r < 4; ++r) {
            const float v = C2[r];
            gs += v; gss += v * v;
            (&st.x)[r] = v;
        }
        *(float4*)(out + ((size_t)b * 64 + g * CG + lr) * HW + pix0 + lj * 4) = st;
    }

    red[tid] = gs; red[256 + tid] = gss;
    __syncthreads();
    for (int st2 = 128; st2 > 0; st2 >>= 1) {
        if (tid < st2) {
            red[tid]       += red[tid + st2];
            red[256 + tid] += red[256 + tid + st2];
        }
        __syncthreads();
    }
    if (tid == 0) {
        partials[(bg * 128 + row) * 2]     = red[0];
        partials[(bg * 128 + row) * 2 + 1] = red[256];
    }
}

// ---- gn_gelu2: fused GN-finalize + apply + exact GELU -----------------------
__global__ __launch_bounds__(256) void gn_gelu2(float* __restrict__ out,
                                                const float* __restrict__ partials,
                                                const float* __restrict__ gn_w,
                                                const float* __restrict__ gn_b)
{
    const int blk = blockIdx.x;
    const int tid = threadIdx.x;
    const int bc  = blk >> 4;            // 16 blocks per (b,c)
    const int c   = bc & 63;
    const int bg  = ((bc >> 6) << 2) + (c >> 4);

    __shared__ float ls[256];
    ls[tid] = partials[bg * 256 + tid];
    __syncthreads();
    #pragma unroll
    for (int st = 128; st >= 2; st >>= 1) {      // even strides preserve parity
        if (tid < st) ls[tid] += ls[tid + st];
        __syncthreads();
    }
    const float n  = (float)(CG * HW);
    const float mu = ls[0] / n;
    const float rs = rsqrtf(ls[1] / n - mu * mu + 1e-5f);
    const float sw = gn_w[c] * rs;
    const float sb = gn_b[c] - mu * sw;

    const int idx = blk * 256 + tid;
    float4 v = ((const float4*)out)[idx];
    float rr[4] = {v.x, v.y, v.z, v.w};
    #pragma unroll
    for (int jj = 0; jj < 4; ++jj) {
        const float t = rr[jj] * sw + sb;
        rr[jj] = t * 0.5f * (1.0f + erff(t * 0.70710678118654752f));
    }
    ((float4*)out)[idx] = make_float4(rr[0], rr[1], rr[2], rr[3]);
}

// ============================ FALLBACK PATH (R7-proven, [pix][64] layout) ====

__global__ __launch_bounds__(256) void transpose_pack(const float* __restrict__ x,
                                                      _Float16* __restrict__ xt)
{
    const int t   = blockIdx.x * 256 + threadIdx.x;
    const int qq  = t & 3;
    const int p2  = t >> 2;
    const int pix = p2 & (HW - 1);
    const int b   = p2 >> 14;
    const float* xs = x + ((size_t)b * C_IN + qq * 16) * HW + pix;
    F16Frag f0, f1;
    #pragma unroll
    for (int j = 0; j < 8; ++j) f0.h[j] = (_Float16)xs[(size_t)j * HW];
    #pragma unroll
    for (int j = 0; j < 8; ++j) f1.h[j] = (_Float16)xs[(size_t)(8 + j) * HW];
    uint4* dst = (uint4*)(xt + ((size_t)b * HW + pix) * 64 + qq * 16);
    dst[0] = f0.q;
    dst[1] = f1.q;
}

__global__ __launch_bounds__(256, 4) void dcn_fused_fb(
    const _Float16* __restrict__ xt,
    const float* __restrict__ w_om,
    const float* __restrict__ b_om,
    const float* __restrict__ dcn_w,
    const float* __restrict__ dcn_b,
    const float* __restrict__ offset_scale,
    float* __restrict__ out,
    float* __restrict__ partials)
{
    const int tid = threadIdx.x;
    const int blk = blockIdx.x;
    const int xcd = blk & 7;
    const int q   = blk >> 3;
    const int bg  = xcd * 2 + (q >> 6);
    const int tb  = q & 63;
    const int b   = bg >> 2, g = bg & 3;
    const int wave = tid >> 6, lane = tid & 63;
    const int lr = lane & 15, lj = lane >> 4;

    __shared__ float om_lds[4][16][33];
    __shared__ float red[512];

    F16Frag B1[2][2];
    #pragma unroll
    for (int s = 0; s < 2; ++s)
    #pragma unroll
    for (int nt = 0; nt < 2; ++nt) {
        const int o = nt * 16 + lr;
        if (o < 27) {
            const float* src = w_om + (size_t)(g * 27 + o) * C_IN + s * 32 + lj * 8;
            #pragma unroll
            for (int e = 0; e < 8; ++e) B1[s][nt].h[e] = (_Float16)src[e];
        } else {
            #pragma unroll
            for (int e = 0; e < 4; ++e) B1[s][nt].w[e] = 0u;
        }
    }
    F16Frag B2[5];
    #pragma unroll
    for (int s = 0; s < 5; ++s) {
        const int kp  = 2 * s + (lj >> 1);
        const int cib = (lj & 1) * 8;
        if (kp < 9) {
            const float* src = dcn_w + ((size_t)(g * CG + lr) * CG + cib) * 9 + kp;
            #pragma unroll
            for (int e = 0; e < 8; ++e) B2[s].h[e] = (_Float16)src[(size_t)e * 9];
        } else {
            #pragma unroll
            for (int e = 0; e < 4; ++e) B2[s].w[e] = 0u;
        }
    }

    const float scale = offset_scale[0];
    const float bo0   = b_om[g * 27 + lr];
    const float bo1   = (lr < 11) ? b_om[g * 27 + 16 + lr] : 0.0f;
    const float cbias = dcn_b[g * CG + lr];

    const _Float16* xtb = xt + (size_t)b * HW * 64;
    const _Float16* xg  = xtb + g * CG + (lj & 1) * 8;
    float gs = 0.0f, gss = 0.0f;

    for (int t = 0; t < 4; ++t) {
        const int pix0 = tb * 256 + wave * 64 + t * 16;
        const int row  = pix0 >> 7;
        const int col0 = pix0 & 127;

        f32x4 C0 = {0, 0, 0, 0}, C1 = {0, 0, 0, 0};
        #pragma unroll
        for (int s = 0; s < 2; ++s) {
            F16Frag A;
            A.q = *(const uint4*)(xtb + (size_t)(pix0 + lr) * 64 + s * 32 + lj * 8);
            C0 = __builtin_amdgcn_mfma_f32_16x16x32_f16(A.f, B1[s][0].f, C0, 0, 0, 0);
            C1 = __builtin_amdgcn_mfma_f32_16x16x32_f16(A.f, B1[s][1].f, C1, 0, 0, 0);
        }
        #pragma unroll
        for (int r = 0; r < 4; ++r) {
            const int prow = lj * 4 + r;
            om_lds[wave][prow][lr] = (C0[r] + bo0) * scale;
            const float v1 = C1[r] + bo1;
            const int o1 = 16 + lr;
            om_lds[wave][prow][o1] = (o1 < 18) ? v1 * scale
                                   : 1.0f / (1.0f + __expf(-v1));
        }

        f32x4 C2 = {cbias, cbias, cbias, cbias};
        #pragma unroll
        for (int s = 0; s < 5; ++s) {
            const int  kp  = 2 * s + (lj >> 1);
            const bool kok = (kp < 9);
            const int  kc  = kok ? kp : 8;
            const float offy = om_lds[wave][lr][2 * kc];
            const float offx = om_lds[wave][lr][2 * kc + 1];
            const float m    = kok ? om_lds[wave][lr][18 + kc] : 0.0f;
            const float py = (float)(row  - PAD + kc / 3) + offy;
            const float px = (float)(col0 + lr - PAD + kc % 3) + offx;

            const float y0f = floorf(py), x0f = floorf(px);
            const int   y0  = (int)y0f,   x0  = (int)x0f;
            const float wy1 = py - y0f,   wx1 = px - x0f;
            const float wy0 = 1.0f - wy1, wx0 = 1.0f - wx1;
            const bool vy0 = (y0 >= 0)  & (y0 <  HH);
            const bool vy1 = (y0 >= -1) & (y0 <  HH - 1);
            const bool vx0 = (x0 >= 0)  & (x0 <  WW);
            const bool vx1 = (x0 >= -1) & (x0 <  WW - 1);
            const int yi0 = min(max(y0,     0), HH - 1);
            const int yi1 = min(max(y0 + 1, 0), HH - 1);
            const int xi0 = min(max(x0,     0), WW - 1);
            const int xi1 = min(max(x0 + 1, 0), WW - 1);
            const float my0 = wy0 * m, my1 = wy1 * m;
            const float w00 = (vy0 & vx0) ? my0 * wx0 : 0.0f;
            const float w01 = (vy0 & vx1) ? my0 * wx1 : 0.0f;
            const float w10 = (vy1 & vx0) ? my1 * wx0 : 0.0f;
            const float w11 = (vy1 & vx1) ? my1 * wx1 : 0.0f;

            F16Frag t00, t01, t10, t11;
            t00.q = *(const uint4*)(xg + (size_t)(yi0 * WW + xi0) * 64);
            t01.q = *(const uint4*)(xg + (size_t)(yi0 * WW + xi1) * 64);
            t10.q = *(const uint4*)(xg + (size_t)(yi1 * WW + xi0) * 64);
            t11.q = *(const uint4*)(xg + (size_t)(yi1 * WW + xi1) * 64);

            const _Float16 h00 = (_Float16)w00, h01 = (_Float16)w01;
            const _Float16 h10 = (_Float16)w10, h11 = (_Float16)w11;
            const f16x2 W00 = {h00, h00}, W01 = {h01, h01};
            const f16x2 W10 = {h10, h10}, W11 = {h11, h11};

            F16Frag A;
            #pragma unroll
            for (int d = 0; d < 4; ++d) {
                f16x2 acc = t00.p[d] * W00;
                acc += t01.p[d] * W01;
                acc += t10.p[d] * W10;
                acc += t11.p[d] * W11;
                A.p[d] = acc;
            }
            C2 = __builtin_amdgcn_mfma_f32_16x16x32_f16(A.f, B2[s].f, C2, 0, 0, 0);
        }

        float4 st;
        #pragma unroll
        for (int r = 0; r < 4; ++r) {
            const float v = C2[r];
            gs += v; gss += v * v;
            (&st.x)[r] = v;
        }
        *(float4*)(out + ((size_t)b * 64 + g * CG + lr) * HW + pix0 + lj * 4) = st;
    }

    red[tid] = gs; red[256 + tid] = gss;
    __syncthreads();
    for (int st2 = 128; st2 > 0; st2 >>= 1) {
        if (tid < st2) {
            red[tid]       += red[tid + st2];
            red[256 + tid] += red[256 + tid + st2];
        }
        __syncthreads();
    }
    if (tid == 0) {
        partials[(bg * 64 + tb) * 2]     = red[0];
        partials[(bg * 64 + tb) * 2 + 1] = red[256];
    }
}

__global__ __launch_bounds__(64) void gn_finalize(const float* __restrict__ partials,
                                                  float* __restrict__ stats,
                                                  int per_bg)
{
    const int bg = blockIdx.x;
    const int t  = threadIdx.x;
    float s = 0.0f, ss = 0.0f;
    for (int i = t; i < per_bg; i += 64) {
        s  += partials[(bg * per_bg + i) * 2];
        ss += partials[(bg * per_bg + i) * 2 + 1];
    }
    #pragma unroll
    for (int off = 32; off > 0; off >>= 1) {
        s  += __shfl_down(s, off);
        ss += __shfl_down(ss, off);
    }
    if (t == 0) {
        const float n   = (float)(CG * HW);
        const float mu  = s / n;
        const float var = ss / n - mu * mu;
        stats[bg * 2]     = mu;
        stats[bg * 2 + 1] = rsqrtf(var + 1e-5f);
    }
}

__global__ __launch_bounds__(256) void gn_gelu(float* __restrict__ out,
                                               const float* __restrict__ stats,
                                               const float* __restrict__ gn_w,
                                               const float* __restrict__ gn_b)
{
    const int idx = blockIdx.x * 256 + threadIdx.x;
    const int bc  = idx >> 12;
    const int c   = bc & 63;
    const int bg  = ((bc >> 6) << 2) + (c >> 4);

    const float mu = stats[bg * 2];
    const float rs = stats[bg * 2 + 1];
    const float sw = gn_w[c] * rs;
    const float sb = gn_b[c] - mu * sw;

    float4 v = ((const float4*)out)[idx];
    float rr[4] = {v.x, v.y, v.z, v.w};
    #pragma unroll
    for (int jj = 0; jj < 4; ++jj) {
        const float t = rr[jj] * sw + sb;
        rr[jj] = t * 0.5f * (1.0f + erff(t * 0.70710678118654752f));
    }
    ((float4*)out)[idx] = make_float4(rr[0], rr[1], rr[2], rr[3]);
}

// ============================ launch =========================================

extern "C" void kernel_launch(void* const* d_in, const int* in_sizes, int n_in,
                              void* d_out, int out_size, void* d_ws, size_t ws_size,
                              hipStream_t stream) {
    const float* x            = (const float*)d_in[0];
    const float* w_om         = (const float*)d_in[1];
    const float* b_om         = (const float*)d_in[2];
    const float* dcn_w        = (const float*)d_in[3];
    const float* dcn_b        = (const float*)d_in[4];
    const float* gn_w         = (const float*)d_in[5];
    const float* gn_b         = (const float*)d_in[6];
    const float* offset_scale = (const float*)d_in[7];
    float* out = (float*)d_out;
    char*  ws  = (char*)d_ws;

    _Float16* xt = (_Float16*)(ws + XT_OFF);

    if (ws_size >= NEED_BYTES) {
        _Float16* om_yx  = (_Float16*)(ws + OMYX_OFF);
        _Float16* om_m   = (_Float16*)(ws + OMM_OFF);
        uint4* frags1    = (uint4*)(ws + FR1_OFF);
        uint4* frags2    = (uint4*)(ws + FR2_OFF);
        float* partials  = (float*)(ws + PART_OFF);

        make_frags<<<9, 256, 0, stream>>>(w_om, dcn_w, frags1, frags2);
        om_gemm_t<<<1024, 256, 0, stream>>>(x, frags1, b_om, offset_scale,
                                            xt, om_yx, om_m);
        dcn_sample<<<2048, 256, 0, stream>>>(xt, (const uint*)om_yx, om_m,
                                             frags2, dcn_b, out, partials);
        gn_gelu2<<<4096, 256, 0, stream>>>(out, partials, gn_w, gn_b);
    } else {
        float* partials = (float*)(ws + FB_PART_OFF);
        float* stats    = (float*)(ws + FB_STATS_OFF);
        transpose_pack<<<1024, 256, 0, stream>>>(x, xt);
        dcn_fused_fb<<<1024, 256, 0, stream>>>(xt, w_om, b_om, dcn_w, dcn_b,
                                               offset_scale, out, partials);
        gn_finalize<<<16, 64, 0, stream>>>(partials, stats, 64);
        gn_gelu<<<(BB * 64 * HW / 4) / 256, 256, 0, stream>>>(out, stats, gn_w, gn_b);
    }
}